// Round 4
// baseline (750.625 us; speedup 1.0000x reference)
//
#include <hip/hip_runtime.h>
#include <hip/hip_bf16.h>
#include <cstdint>

// ---------------------------------------------------------------------------
// ImageEncoder: 4-layer transformer encoder, N=4 S=2048 D=512 H=8 HD=64 F=200.
// fp32 residual stream + bf16 MFMA.
// R4: attention — P kept in registers (S^T C-layout == K=16 PV A-layout),
// Pt LDS round-trip deleted; Vt stride 68 for conflict-free b64 reads.
// GEMM mode 0 fuses residual add; LN single-input.
// ---------------------------------------------------------------------------

typedef __bf16 bf16;
typedef __bf16 bf16x8 __attribute__((ext_vector_type(8)));
typedef __bf16 bf16x4 __attribute__((ext_vector_type(4)));
typedef short short4v __attribute__((ext_vector_type(4)));
typedef float f32x4 __attribute__((ext_vector_type(4)));

#define MFMA16(a, b, c) __builtin_amdgcn_mfma_f32_16x16x32_bf16((a), (b), (c), 0, 0, 0)

// K=16 MFMA: D[m=lane&15][k-free]; A 2 VGPRs (4 bf16, k=quad*4+j)
__device__ __forceinline__ f32x4 mfma_k16(bf16x4 a, bf16x4 b, f32x4 c) {
#if __has_builtin(__builtin_amdgcn_mfma_f32_16x16x16_bf16)
    return __builtin_amdgcn_mfma_f32_16x16x16_bf16(a, b, c, 0, 0, 0);
#else
    short4v as, bs;
    __builtin_memcpy(&as, &a, 8);
    __builtin_memcpy(&bs, &b, 8);
    return __builtin_amdgcn_mfma_f32_16x16x16bf16_1k(as, bs, c, 0, 0, 0);
#endif
}

static constexpr int NB   = 4;
static constexpr int SQ   = 2048;
static constexpr int DM   = 512;
static constexpr int NH   = 8;
static constexpr int HD   = 64;
static constexpr int NL   = 4;
static constexpr int FF   = 200;
static constexpr int FFP  = 256;
static constexpr int MTOK = NB * SQ; // 8192

__device__ __forceinline__ float fast_exp2(float x) {
#if __has_builtin(__builtin_amdgcn_exp2f)
    return __builtin_amdgcn_exp2f(x);
#else
    return exp2f(x);
#endif
}

// async global->LDS, 16 bytes per lane
__device__ __forceinline__ void gld16(bf16* l, const bf16* g) {
    __builtin_amdgcn_global_load_lds(
        (const __attribute__((address_space(1))) void*)g,
        (__attribute__((address_space(3))) void*)l, 16, 0, 0);
}

// ---------------------------------------------------------------------------
// Weight convert + transpose:  src fp32 [K, Nsrc]  ->  dst bf16 [Npad, Kpad]
// ---------------------------------------------------------------------------
__global__ __launch_bounds__(256) void convw_kernel(
    const float* __restrict__ Wq, const float* __restrict__ Wk,
    const float* __restrict__ Wv, const float* __restrict__ Wo,
    const float* __restrict__ W1, const float* __restrict__ W2,
    bf16* __restrict__ wqkvt, bf16* __restrict__ wot,
    bf16* __restrict__ w1t, bf16* __restrict__ w2t)
{
    __shared__ float tile[32][33];
    const int z = blockIdx.z, l = z / 6, which = z % 6;
    const float* src; bf16* dst; int K, Nsrc, Npad, Kpad;
    switch (which) {
        case 0: src = Wq + (size_t)l*DM*DM; dst = wqkvt + (size_t)(l*3+0)*DM*DM; K=DM; Nsrc=DM; Npad=DM; Kpad=DM; break;
        case 1: src = Wk + (size_t)l*DM*DM; dst = wqkvt + (size_t)(l*3+1)*DM*DM; K=DM; Nsrc=DM; Npad=DM; Kpad=DM; break;
        case 2: src = Wv + (size_t)l*DM*DM; dst = wqkvt + (size_t)(l*3+2)*DM*DM; K=DM; Nsrc=DM; Npad=DM; Kpad=DM; break;
        case 3: src = Wo + (size_t)l*DM*DM; dst = wot   + (size_t)l*DM*DM;       K=DM; Nsrc=DM; Npad=DM; Kpad=DM; break;
        case 4: src = W1 + (size_t)l*DM*FF; dst = w1t   + (size_t)l*FFP*DM;      K=DM; Nsrc=FF; Npad=FFP; Kpad=DM; break;
        default:src = W2 + (size_t)l*FF*DM; dst = w2t   + (size_t)l*DM*FFP;      K=FF; Nsrc=DM; Npad=DM; Kpad=FFP; break;
    }
    const int k0 = blockIdx.x * 32, n0 = blockIdx.y * 32;
    if (k0 >= Kpad || n0 >= Npad) return;
    const int tr = threadIdx.x >> 3, tc = (threadIdx.x & 7) * 4;
    for (int c = 0; c < 4; c++) {
        int sr = k0 + tr, sc = n0 + tc + c;
        tile[tr][tc + c] = (sr < K && sc < Nsrc) ? src[(size_t)sr * Nsrc + sc] : 0.f;
    }
    __syncthreads();
    const int dr = n0 + tr;
    if (dr < Npad) {
        for (int c = 0; c < 4; c++) {
            int dc = k0 + tc + c;
            if (dc < Kpad) dst[(size_t)dr * Kpad + dc] = (bf16)tile[tc + c][tr];
        }
    }
}

// ---------------------------------------------------------------------------
// Positional encoding add + cast
// ---------------------------------------------------------------------------
__global__ __launch_bounds__(256) void posenc_kernel(
    const float* __restrict__ f, float* __restrict__ x, bf16* __restrict__ xb)
{
    const int t = blockIdx.x * 256 + threadIdx.x;
    const int d2 = t & 255, row = t >> 8, s = row & (SQ - 1);
    const float kfac = -0.03597789207803197f;           // -2*ln(10000)/512
    float dv = __expf((float)d2 * kfac);
    float ang = (float)s * dv;
    float pe0 = sinf(ang), pe1 = cosf(ang);
    const size_t base = (size_t)row * DM + d2 * 2;
    float2 fv = *(const float2*)(f + base);
    float o0 = fv.x + pe0, o1 = fv.y + pe1;
    *(float2*)(x + base) = make_float2(o0, o1);
    union { bf16 h[2]; unsigned int u; } pk;
    pk.h[0] = (bf16)o0; pk.h[1] = (bf16)o1;
    *(unsigned int*)(xb + base) = pk.u;
}

// ---------------------------------------------------------------------------
// m97-style GEMM core: block tile 128x128, BK=32, 4 waves (2x2 of 64x64).
// ---------------------------------------------------------------------------
__device__ __forceinline__ void gemm128_core(
    const bf16* __restrict__ A, const bf16* __restrict__ Wt, int K,
    int m0, int n0, bf16* As, bf16* Bs, f32x4 (&acc)[4][4])
{
    const int tid = threadIdx.x;
    const int w = tid >> 6, lane = tid & 63;
    const int l15 = lane & 15, quad = lane >> 4;
    const int srow = w * 16 + (lane >> 2);
    const int scol = (lane & 3) * 8;
    const bf16* Ag = A  + (size_t)(m0 + srow) * K + scol;
    const bf16* Bg = Wt + (size_t)(n0 + srow) * K + scol;
    bf16* AsW = As + w * 512;
    bf16* BsW = Bs + w * 512;
    const int wm = (w >> 1) * 64, wn = (w & 1) * 64;

    for (int k0 = 0; k0 < K; k0 += 32) {
        __syncthreads();
        gld16(AsW,        Ag + k0);
        gld16(AsW + 2048, Ag + (size_t)64 * K + k0);
        gld16(BsW,        Bg + k0);
        gld16(BsW + 2048, Bg + (size_t)64 * K + k0);
        asm volatile("s_waitcnt vmcnt(0)" ::: "memory");
        __syncthreads();

        bf16x8 af[4], bfr[4];
        #pragma unroll
        for (int i = 0; i < 4; i++)
            af[i] = *(const bf16x8*)&As[(wm + i * 16 + l15) * 32 + quad * 8];
        #pragma unroll
        for (int j = 0; j < 4; j++)
            bfr[j] = *(const bf16x8*)&Bs[(wn + j * 16 + l15) * 32 + quad * 8];
        #pragma unroll
        for (int i = 0; i < 4; i++)
            #pragma unroll
            for (int j = 0; j < 4; j++)
                acc[i][j] = MFMA16(af[i], bfr[j], acc[i][j]);
    }
}

// modes: 0 fp32 out (+resid if non-null), 1 bf16 out, 2 bf16 relu
__global__ __launch_bounds__(256, 2) void gemm128_kernel(
    const bf16* __restrict__ A, const bf16* __restrict__ Wt,
    const float* __restrict__ bias, int nbias,
    const float* __restrict__ resid,
    float* __restrict__ outf, bf16* __restrict__ outb,
    int K, int Nc, int mode)
{
    __shared__ alignas(16) bf16 As[128 * 32];
    __shared__ alignas(16) bf16 Bs[128 * 32];
    const int m0 = blockIdx.x * 128, n0 = blockIdx.y * 128;
    f32x4 acc[4][4] = {};
    gemm128_core(A, Wt, K, m0, n0, As, Bs, acc);

    const int lane = threadIdx.x & 63;
    const int l15 = lane & 15, quad = lane >> 4;
    const int w = threadIdx.x >> 6;
    const int wm = (w >> 1) * 64, wn = (w & 1) * 64;
    #pragma unroll
    for (int j = 0; j < 4; j++) {
        const int col = n0 + wn + j * 16 + l15;
        const float bv = (col < nbias) ? bias[col] : 0.f;
        #pragma unroll
        for (int i = 0; i < 4; i++) {
            const int rbase = m0 + wm + i * 16 + quad * 4;
            #pragma unroll
            for (int r = 0; r < 4; r++) {
                float v = acc[i][j][r] + bv;
                const int row = rbase + r;
                const size_t idx = (size_t)row * Nc + col;
                if (mode == 0)      outf[idx] = v + (resid ? resid[idx] : 0.f);
                else if (mode == 1) outb[idx] = (bf16)v;
                else                outb[idx] = (bf16)fmaxf(v, 0.f);
            }
        }
    }
}

// fused QKV. Q gets (1/sqrt(HD))*log2(e) folded in (softmax uses exp2);
// V written transposed to [n,h,hd,s].
__global__ __launch_bounds__(256, 2) void gemm128_qkv_kernel(
    const bf16* __restrict__ xb, const bf16* __restrict__ Wt,
    const float* __restrict__ bq, const float* __restrict__ bk,
    const float* __restrict__ bv,
    bf16* __restrict__ qb, bf16* __restrict__ kb, bf16* __restrict__ vtb)
{
    __shared__ alignas(16) bf16 As[128 * 32];
    __shared__ alignas(16) bf16 Bs[128 * 32];
    const int m0 = blockIdx.x * 128, n0 = blockIdx.y * 128;
    f32x4 acc[4][4] = {};
    gemm128_core(xb, Wt, DM, m0, n0, As, Bs, acc);

    const int lane = threadIdx.x & 63;
    const int l15 = lane & 15, quad = lane >> 4;
    const int w = threadIdx.x >> 6;
    const int wm = (w >> 1) * 64, wn = (w & 1) * 64;
    const int which = n0 >> 9;
    const float* bias = (which == 0) ? bq : (which == 1) ? bk : bv;
    // 0.125 = 1/sqrt(64); *1.44269504 so attn can use exp2 directly
    const float scale = (which == 0) ? 0.18033688f : 1.f;
    #pragma unroll
    for (int j = 0; j < 4; j++) {
        const int c = (n0 & 511) + wn + j * 16 + l15;
        const float bvv = bias[c];
        #pragma unroll
        for (int i = 0; i < 4; i++) {
            const int rbase = m0 + wm + i * 16 + quad * 4;
            #pragma unroll
            for (int r = 0; r < 4; r++) {
                float v = (acc[i][j][r] + bvv) * scale;
                const int row = rbase + r;
                if (which == 0)      qb[(size_t)row * DM + c] = (bf16)v;
                else if (which == 1) kb[(size_t)row * DM + c] = (bf16)v;
                else {
                    const int n = row >> 11, s = row & (SQ - 1);
                    const int h = c >> 6, hd = c & 63;
                    vtb[((size_t)(((n << 3) | h) << 6 | hd) << 11) | s] = (bf16)v;
                }
            }
        }
    }
}

// ---------------------------------------------------------------------------
// Flash attention, R4. Block: one (n,h), 128 q-rows (4 waves x 32 q).
// S^T = K·Q^T (16x16x32): lane holds q=l15, kv=quad*4+r — which IS the
// A-fragment layout of the K=16 PV MFMA. P never touches LDS.
// Vt row stride 68 el (34 dw): b64 spans (l15+4*t3)%16 — conflict-free.
// Kt row stride 72 el: b128 spans uniform. Double-buffered, 1 sync/iter.
// ---------------------------------------------------------------------------
__global__ __launch_bounds__(256, 2) void attn_kernel(
    const bf16* __restrict__ qb, const bf16* __restrict__ kb,
    const bf16* __restrict__ vtb, bf16* __restrict__ yb)
{
    __shared__ alignas(16) bf16 Kt[2][64][72];
    __shared__ alignas(16) bf16 Vt[2 * 64 * 68];
    const int tid = threadIdx.x;
    const int w = tid >> 6, lane = tid & 63;
    const int l15 = lane & 15, quad = lane >> 4;
    // XCD-aware decode: all 16 q-blocks of one (n,h) land on one XCD
    const int id = blockIdx.x;
    const int nh = (id & 7) * 4 + ((id >> 3) & 3);
    const int qblk = id >> 5;
    const int n = nh >> 3, h = nh & 7;
    const int q0 = qblk * 128 + w * 32;
    const bf16* qbase = qb + (size_t)n * SQ * DM + h * HD;
    const bf16* kbase = kb + (size_t)n * SQ * DM + h * HD;
    const bf16* vbase = vtb + (size_t)nh * HD * SQ;

    // Q fragments (B-operand of S^T: n=q=l15, k=d=quad*8+j)
    bf16x8 qf[2][2];
    for (int mi = 0; mi < 2; mi++)
        for (int hh = 0; hh < 2; hh++)
            qf[mi][hh] = *(const bf16x8*)(qbase + (size_t)(q0 + mi*16 + l15) * DM + hh*32 + quad*8);

    f32x4 o[2][4] = {};
    float lsum[2] = {0.f, 0.f};

    // staging: thread covers (srow, seg..seg+16) of the 64x64 tile
    const int srow = tid >> 2, seg = (tid & 3) * 16;
    const bf16* krow = kbase + (size_t)srow * DM + seg;  // K rows = kv
    const bf16* vrow = vbase + (size_t)srow * SQ + seg;  // V rows = hd

    auto storeV = [&](int buf, bf16x8 a, bf16x8 b) {
        bf16* d = &Vt[(buf * 64 + srow) * 68 + seg];
        bf16x4 p0, p1, p2, p3;
        #pragma unroll
        for (int i = 0; i < 4; i++) { p0[i]=a[i]; p1[i]=a[i+4]; p2[i]=b[i]; p3[i]=b[i+4]; }
        *(bf16x4*)(d)      = p0;
        *(bf16x4*)(d + 4)  = p1;
        *(bf16x4*)(d + 8)  = p2;
        *(bf16x4*)(d + 12) = p3;
    };

    { // prologue: stage tile 0
        bf16x8 k0 = *(const bf16x8*)(krow);
        bf16x8 k1 = *(const bf16x8*)(krow + 8);
        bf16x8 v0 = *(const bf16x8*)(vrow);
        bf16x8 v1 = *(const bf16x8*)(vrow + 8);
        *(bf16x8*)&Kt[0][srow][seg]     = k0;
        *(bf16x8*)&Kt[0][srow][seg + 8] = k1;
        storeV(0, v0, v1);
    }

    for (int jt = 0; jt < SQ / 64; jt++) {
        const int buf = jt & 1;
        __syncthreads();   // buf writes visible; prev iter's reads complete
        const bool pre = (jt + 1 < SQ / 64);
        bf16x8 k0, k1, v0, v1;
        if (pre) {         // next tile's global loads issued early
            const bf16* kp = krow + (size_t)(jt + 1) * 64 * DM;
            const bf16* vp = vrow + (jt + 1) * 64;
            k0 = *(const bf16x8*)(kp);
            k1 = *(const bf16x8*)(kp + 8);
            v0 = *(const bf16x8*)(vp);
            v1 = *(const bf16x8*)(vp + 8);
        }

        #pragma unroll
        for (int s4 = 0; s4 < 4; s4++) {
            // K A-frag (m=kv), Q B-frag -> S^T[kv][q]
            bf16x8 kf0 = *(const bf16x8*)&Kt[buf][s4*16 + l15][quad*8];
            bf16x8 kf1 = *(const bf16x8*)&Kt[buf][s4*16 + l15][32 + quad*8];
            bf16x4 pf[2];
            #pragma unroll
            for (int mi = 0; mi < 2; mi++) {
                f32x4 sacc = {};
                sacc = MFMA16(kf0, qf[mi][0], sacc);
                sacc = MFMA16(kf1, qf[mi][1], sacc);
                float p0 = fast_exp2(sacc[0]);
                float p1 = fast_exp2(sacc[1]);
                float p2 = fast_exp2(sacc[2]);
                float p3 = fast_exp2(sacc[3]);
                lsum[mi] += (p0 + p1) + (p2 + p3);
                bf16x4 pk;
                pk[0] = (bf16)p0; pk[1] = (bf16)p1;
                pk[2] = (bf16)p2; pk[3] = (bf16)p3;
                pf[mi] = pk;       // == K=16 A-frag: q=l15, kv=quad*4+j
            }
            // O[q][hd] += P V  (K=16 per s4 chunk)
            #pragma unroll
            for (int d4 = 0; d4 < 4; d4++) {
                bf16x4 vf = *(const bf16x4*)&Vt[(buf*64 + d4*16 + l15) * 68 + s4*16 + quad*4];
                o[0][d4] = mfma_k16(pf[0], vf, o[0][d4]);
                o[1][d4] = mfma_k16(pf[1], vf, o[1][d4]);
            }
        }

        if (pre) {
            *(bf16x8*)&Kt[buf^1][srow][seg]     = k0;
            *(bf16x8*)&Kt[buf^1][srow][seg + 8] = k1;
            storeV(buf^1, v0, v1);
        }
    }

    // lsum lives at q=l15 per quad; reduce across quads
    #pragma unroll
    for (int mi = 0; mi < 2; mi++) {
        lsum[mi] += __shfl_xor(lsum[mi], 16, 64);
        lsum[mi] += __shfl_xor(lsum[mi], 32, 64);
    }
    // O rows are q=quad*4+r -> fetch 1/lsum via shuffle from lane q
    #pragma unroll
    for (int mi = 0; mi < 2; mi++) {
        f32x4 rl;
        #pragma unroll
        for (int r = 0; r < 4; r++)
            rl[r] = 1.f / __shfl(lsum[mi], quad * 4 + r, 64);
        #pragma unroll
        for (int d4 = 0; d4 < 4; d4++) {
            const int col = h * HD + d4 * 16 + l15;
            #pragma unroll
            for (int r = 0; r < 4; r++) {
                const int row = n * SQ + q0 + mi*16 + quad*4 + r;
                yb[(size_t)row * DM + col] = (bf16)(o[mi][d4][r] * rl[r]);
            }
        }
    }
}

// ---------------------------------------------------------------------------
// LayerNorm over a precomputed sum stream (residual folded into GEMM epilogue)
// ---------------------------------------------------------------------------
__global__ __launch_bounds__(256) void ln_kernel(
    const float* __restrict__ xin,
    const float* __restrict__ g, const float* __restrict__ beta,
    float* __restrict__ outf, bf16* __restrict__ outb)
{
    const int w = threadIdx.x >> 6, lane = threadIdx.x & 63;
    const size_t row = (size_t)blockIdx.x * 4 + w;
    const float4* rp = (const float4*)(xin + row * DM);
    float4 v[2];
    float s = 0.f, s2 = 0.f;
    #pragma unroll
    for (int i = 0; i < 2; i++) {
        const int idx = i * 64 + lane;
        float4 a = rp[idx];
        v[i] = a;
        s  += a.x + a.y + a.z + a.w;
        s2 += a.x*a.x + a.y*a.y + a.z*a.z + a.w*a.w;
    }
    for (int m = 1; m < 64; m <<= 1) {
        s  += __shfl_xor(s,  m, 64);
        s2 += __shfl_xor(s2, m, 64);
    }
    const float mean = s * (1.f / DM);
    const float var  = s2 * (1.f / DM) - mean * mean;
    const float rstd = rsqrtf(var + 1e-5f);
    #pragma unroll
    for (int i = 0; i < 2; i++) {
        const int idx = i * 64 + lane;
        float4 gw = ((const float4*)g)[idx], bw = ((const float4*)beta)[idx];
        float o0 = (v[i].x - mean) * rstd * gw.x + bw.x;
        float o1 = (v[i].y - mean) * rstd * gw.y + bw.y;
        float o2 = (v[i].z - mean) * rstd * gw.z + bw.z;
        float o3 = (v[i].w - mean) * rstd * gw.w + bw.w;
        ((float4*)(outf + row * DM))[idx] = make_float4(o0, o1, o2, o3);
        union { bf16 h[4]; uint2 u; } pk;
        pk.h[0] = (bf16)o0; pk.h[1] = (bf16)o1; pk.h[2] = (bf16)o2; pk.h[3] = (bf16)o3;
        *(uint2*)(outb + row * DM + idx * 4) = pk.u;
    }
}

// ---------------------------------------------------------------------------
extern "C" void kernel_launch(void* const* d_in, const int* in_sizes, int n_in,
                              void* d_out, int out_size, void* d_ws, size_t ws_size,
                              hipStream_t stream)
{
    const float* features = (const float*)d_in[0];
    const float* Wq  = (const float*)d_in[1];
    const float* bq  = (const float*)d_in[2];
    const float* Wk  = (const float*)d_in[3];
    const float* bk  = (const float*)d_in[4];
    const float* Wv  = (const float*)d_in[5];
    const float* bv  = (const float*)d_in[6];
    const float* Wo  = (const float*)d_in[7];
    const float* bo  = (const float*)d_in[8];
    const float* W1  = (const float*)d_in[9];
    const float* b1  = (const float*)d_in[10];
    const float* W2  = (const float*)d_in[11];
    const float* b2  = (const float*)d_in[12];
    const float* ln1w = (const float*)d_in[13];
    const float* ln1b = (const float*)d_in[14];
    const float* ln2w = (const float*)d_in[15];
    const float* ln2b = (const float*)d_in[16];
    float* outp = (float*)d_out;

    char* p = (char*)d_ws;
    size_t off = 0;
    auto alloc = [&](size_t bytes) { void* r = p + off; off = (off + bytes + 255) & ~(size_t)255; return r; };
    const size_t tokD = (size_t)MTOK * DM;
    float* x     = (float*)alloc(tokD * 4);
    float* tmp   = (float*)alloc(tokD * 4);
    bf16* xb     = (bf16*)alloc(tokD * 2);
    bf16* qb     = (bf16*)alloc(tokD * 2);
    bf16* kb     = (bf16*)alloc(tokD * 2);
    bf16* vtb    = (bf16*)alloc(tokD * 2);
    bf16* yb     = (bf16*)alloc(tokD * 2);
    bf16* ffh    = (bf16*)alloc((size_t)MTOK * FFP * 2);
    bf16* wqkvt  = (bf16*)alloc((size_t)NL * 3 * DM * DM * 2);
    bf16* wot    = (bf16*)alloc((size_t)NL * DM * DM * 2);
    bf16* w1t    = (bf16*)alloc((size_t)NL * FFP * DM * 2);
    bf16* w2t    = (bf16*)alloc((size_t)NL * DM * FFP * 2);
    (void)ws_size; (void)in_sizes; (void)n_in; (void)out_size;

    convw_kernel<<<dim3(16, 16, NL * 6), 256, 0, stream>>>(
        Wq, Wk, Wv, Wo, W1, W2, wqkvt, wot, w1t, w2t);

    posenc_kernel<<<MTOK, 256, 0, stream>>>(features, x, xb);

    for (int l = 0; l < NL; l++) {
        const bf16* wqkvt_l = wqkvt + (size_t)l * 3 * DM * DM;
        gemm128_qkv_kernel<<<dim3(MTOK / 128, 1536 / 128), 256, 0, stream>>>(
            xb, wqkvt_l, bq + l*DM, bk + l*DM, bv + l*DM, qb, kb, vtb);
        attn_kernel<<<512, 256, 0, stream>>>(qb, kb, vtb, yb);
        // tmp = x + yb@Wo + bo   (residual fused)
        gemm128_kernel<<<dim3(MTOK / 128, DM / 128), 256, 0, stream>>>(
            yb, wot + (size_t)l*DM*DM, bo + l*DM, DM, x, tmp, nullptr, DM, DM, 0);
        ln_kernel<<<MTOK / 4, 256, 0, stream>>>(tmp, ln1w + l*DM, ln1b + l*DM, x, xb);
        gemm128_kernel<<<dim3(MTOK / 128, FFP / 128), 256, 0, stream>>>(
            xb, w1t + (size_t)l*FFP*DM, b1 + l*FF, FF, nullptr, nullptr, ffh, DM, FFP, 2);
        // tmp = x + ffh@W2 + b2  (residual fused)
        gemm128_kernel<<<dim3(MTOK / 128, DM / 128), 256, 0, stream>>>(
            ffh, w2t + (size_t)l*DM*FFP, b2 + l*DM, DM, x, tmp, nullptr, FFP, DM, 0);
        float* outdst = (l == NL - 1) ? outp : x;
        ln_kernel<<<MTOK / 4, 256, 0, stream>>>(tmp, ln2w + l*DM, ln2b + l*DM, outdst, xb);
    }
}

// Round 5
// 736.045 us; speedup vs baseline: 1.0198x; 1.0198x over previous
//
#include <hip/hip_runtime.h>
#include <hip/hip_bf16.h>
#include <cstdint>

// ---------------------------------------------------------------------------
// ImageEncoder: 4-layer transformer encoder, N=4 S=2048 D=512 H=8 HD=64 F=200.
// fp32 residual stream + bf16 MFMA.
// R5: revert R4's residual-into-GEMM fusion (scattered resid loads hoisted ->
// VGPR pressure, ~80us regression). Keep R4 attn (register-P). Raise
// occupancy caps: attn (256,4) -> 4 blocks/CU, gemm (256,3) -> 3 blocks/CU.
// ---------------------------------------------------------------------------

typedef __bf16 bf16;
typedef __bf16 bf16x8 __attribute__((ext_vector_type(8)));
typedef __bf16 bf16x4 __attribute__((ext_vector_type(4)));
typedef short short4v __attribute__((ext_vector_type(4)));
typedef float f32x4 __attribute__((ext_vector_type(4)));

#define MFMA16(a, b, c) __builtin_amdgcn_mfma_f32_16x16x32_bf16((a), (b), (c), 0, 0, 0)

// K=16 MFMA: lane holds A[m=l15][k=quad*4+j]
__device__ __forceinline__ f32x4 mfma_k16(bf16x4 a, bf16x4 b, f32x4 c) {
#if __has_builtin(__builtin_amdgcn_mfma_f32_16x16x16_bf16)
    return __builtin_amdgcn_mfma_f32_16x16x16_bf16(a, b, c, 0, 0, 0);
#else
    short4v as, bs;
    __builtin_memcpy(&as, &a, 8);
    __builtin_memcpy(&bs, &b, 8);
    return __builtin_amdgcn_mfma_f32_16x16x16bf16_1k(as, bs, c, 0, 0, 0);
#endif
}

static constexpr int NB   = 4;
static constexpr int SQ   = 2048;
static constexpr int DM   = 512;
static constexpr int NH   = 8;
static constexpr int HD   = 64;
static constexpr int NL   = 4;
static constexpr int FF   = 200;
static constexpr int FFP  = 256;
static constexpr int MTOK = NB * SQ; // 8192

__device__ __forceinline__ float fast_exp2(float x) {
#if __has_builtin(__builtin_amdgcn_exp2f)
    return __builtin_amdgcn_exp2f(x);
#else
    return exp2f(x);
#endif
}

// async global->LDS, 16 bytes per lane
__device__ __forceinline__ void gld16(bf16* l, const bf16* g) {
    __builtin_amdgcn_global_load_lds(
        (const __attribute__((address_space(1))) void*)g,
        (__attribute__((address_space(3))) void*)l, 16, 0, 0);
}

// ---------------------------------------------------------------------------
// Weight convert + transpose:  src fp32 [K, Nsrc]  ->  dst bf16 [Npad, Kpad]
// ---------------------------------------------------------------------------
__global__ __launch_bounds__(256) void convw_kernel(
    const float* __restrict__ Wq, const float* __restrict__ Wk,
    const float* __restrict__ Wv, const float* __restrict__ Wo,
    const float* __restrict__ W1, const float* __restrict__ W2,
    bf16* __restrict__ wqkvt, bf16* __restrict__ wot,
    bf16* __restrict__ w1t, bf16* __restrict__ w2t)
{
    __shared__ float tile[32][33];
    const int z = blockIdx.z, l = z / 6, which = z % 6;
    const float* src; bf16* dst; int K, Nsrc, Npad, Kpad;
    switch (which) {
        case 0: src = Wq + (size_t)l*DM*DM; dst = wqkvt + (size_t)(l*3+0)*DM*DM; K=DM; Nsrc=DM; Npad=DM; Kpad=DM; break;
        case 1: src = Wk + (size_t)l*DM*DM; dst = wqkvt + (size_t)(l*3+1)*DM*DM; K=DM; Nsrc=DM; Npad=DM; Kpad=DM; break;
        case 2: src = Wv + (size_t)l*DM*DM; dst = wqkvt + (size_t)(l*3+2)*DM*DM; K=DM; Nsrc=DM; Npad=DM; Kpad=DM; break;
        case 3: src = Wo + (size_t)l*DM*DM; dst = wot   + (size_t)l*DM*DM;       K=DM; Nsrc=DM; Npad=DM; Kpad=DM; break;
        case 4: src = W1 + (size_t)l*DM*FF; dst = w1t   + (size_t)l*FFP*DM;      K=DM; Nsrc=FF; Npad=FFP; Kpad=DM; break;
        default:src = W2 + (size_t)l*FF*DM; dst = w2t   + (size_t)l*DM*FFP;      K=FF; Nsrc=DM; Npad=DM; Kpad=FFP; break;
    }
    const int k0 = blockIdx.x * 32, n0 = blockIdx.y * 32;
    if (k0 >= Kpad || n0 >= Npad) return;
    const int tr = threadIdx.x >> 3, tc = (threadIdx.x & 7) * 4;
    for (int c = 0; c < 4; c++) {
        int sr = k0 + tr, sc = n0 + tc + c;
        tile[tr][tc + c] = (sr < K && sc < Nsrc) ? src[(size_t)sr * Nsrc + sc] : 0.f;
    }
    __syncthreads();
    const int dr = n0 + tr;
    if (dr < Npad) {
        for (int c = 0; c < 4; c++) {
            int dc = k0 + tc + c;
            if (dc < Kpad) dst[(size_t)dr * Kpad + dc] = (bf16)tile[tc + c][tr];
        }
    }
}

// ---------------------------------------------------------------------------
// Positional encoding add + cast
// ---------------------------------------------------------------------------
__global__ __launch_bounds__(256) void posenc_kernel(
    const float* __restrict__ f, float* __restrict__ x, bf16* __restrict__ xb)
{
    const int t = blockIdx.x * 256 + threadIdx.x;
    const int d2 = t & 255, row = t >> 8, s = row & (SQ - 1);
    const float kfac = -0.03597789207803197f;           // -2*ln(10000)/512
    float dv = __expf((float)d2 * kfac);
    float ang = (float)s * dv;
    float pe0 = sinf(ang), pe1 = cosf(ang);
    const size_t base = (size_t)row * DM + d2 * 2;
    float2 fv = *(const float2*)(f + base);
    float o0 = fv.x + pe0, o1 = fv.y + pe1;
    *(float2*)(x + base) = make_float2(o0, o1);
    union { bf16 h[2]; unsigned int u; } pk;
    pk.h[0] = (bf16)o0; pk.h[1] = (bf16)o1;
    *(unsigned int*)(xb + base) = pk.u;
}

// ---------------------------------------------------------------------------
// m97-style GEMM core: block tile 128x128, BK=32, 4 waves (2x2 of 64x64).
// ---------------------------------------------------------------------------
__device__ __forceinline__ void gemm128_core(
    const bf16* __restrict__ A, const bf16* __restrict__ Wt, int K,
    int m0, int n0, bf16* As, bf16* Bs, f32x4 (&acc)[4][4])
{
    const int tid = threadIdx.x;
    const int w = tid >> 6, lane = tid & 63;
    const int l15 = lane & 15, quad = lane >> 4;
    const int srow = w * 16 + (lane >> 2);
    const int scol = (lane & 3) * 8;
    const bf16* Ag = A  + (size_t)(m0 + srow) * K + scol;
    const bf16* Bg = Wt + (size_t)(n0 + srow) * K + scol;
    bf16* AsW = As + w * 512;
    bf16* BsW = Bs + w * 512;
    const int wm = (w >> 1) * 64, wn = (w & 1) * 64;

    for (int k0 = 0; k0 < K; k0 += 32) {
        __syncthreads();
        gld16(AsW,        Ag + k0);
        gld16(AsW + 2048, Ag + (size_t)64 * K + k0);
        gld16(BsW,        Bg + k0);
        gld16(BsW + 2048, Bg + (size_t)64 * K + k0);
        asm volatile("s_waitcnt vmcnt(0)" ::: "memory");
        __syncthreads();

        bf16x8 af[4], bfr[4];
        #pragma unroll
        for (int i = 0; i < 4; i++)
            af[i] = *(const bf16x8*)&As[(wm + i * 16 + l15) * 32 + quad * 8];
        #pragma unroll
        for (int j = 0; j < 4; j++)
            bfr[j] = *(const bf16x8*)&Bs[(wn + j * 16 + l15) * 32 + quad * 8];
        #pragma unroll
        for (int i = 0; i < 4; i++)
            #pragma unroll
            for (int j = 0; j < 4; j++)
                acc[i][j] = MFMA16(af[i], bfr[j], acc[i][j]);
    }
}

// modes: 0 fp32 out, 1 bf16 out, 2 bf16 relu
__global__ __launch_bounds__(256, 3) void gemm128_kernel(
    const bf16* __restrict__ A, const bf16* __restrict__ Wt,
    const float* __restrict__ bias, int nbias,
    float* __restrict__ outf, bf16* __restrict__ outb,
    int K, int Nc, int mode)
{
    __shared__ alignas(16) bf16 As[128 * 32];
    __shared__ alignas(16) bf16 Bs[128 * 32];
    const int m0 = blockIdx.x * 128, n0 = blockIdx.y * 128;
    f32x4 acc[4][4] = {};
    gemm128_core(A, Wt, K, m0, n0, As, Bs, acc);

    const int lane = threadIdx.x & 63;
    const int l15 = lane & 15, quad = lane >> 4;
    const int w = threadIdx.x >> 6;
    const int wm = (w >> 1) * 64, wn = (w & 1) * 64;
    #pragma unroll
    for (int j = 0; j < 4; j++) {
        const int col = n0 + wn + j * 16 + l15;
        const float bv = (col < nbias) ? bias[col] : 0.f;
        #pragma unroll
        for (int i = 0; i < 4; i++) {
            const int rbase = m0 + wm + i * 16 + quad * 4;
            #pragma unroll
            for (int r = 0; r < 4; r++) {
                float v = acc[i][j][r] + bv;
                const int row = rbase + r;
                const size_t idx = (size_t)row * Nc + col;
                if (mode == 0)      outf[idx] = v;
                else if (mode == 1) outb[idx] = (bf16)v;
                else                outb[idx] = (bf16)fmaxf(v, 0.f);
            }
        }
    }
}

// fused QKV. Q gets (1/sqrt(HD))*log2(e) folded in (softmax uses exp2);
// V written transposed to [n,h,hd,s].
__global__ __launch_bounds__(256, 3) void gemm128_qkv_kernel(
    const bf16* __restrict__ xb, const bf16* __restrict__ Wt,
    const float* __restrict__ bq, const float* __restrict__ bk,
    const float* __restrict__ bv,
    bf16* __restrict__ qb, bf16* __restrict__ kb, bf16* __restrict__ vtb)
{
    __shared__ alignas(16) bf16 As[128 * 32];
    __shared__ alignas(16) bf16 Bs[128 * 32];
    const int m0 = blockIdx.x * 128, n0 = blockIdx.y * 128;
    f32x4 acc[4][4] = {};
    gemm128_core(xb, Wt, DM, m0, n0, As, Bs, acc);

    const int lane = threadIdx.x & 63;
    const int l15 = lane & 15, quad = lane >> 4;
    const int w = threadIdx.x >> 6;
    const int wm = (w >> 1) * 64, wn = (w & 1) * 64;
    const int which = n0 >> 9;
    const float* bias = (which == 0) ? bq : (which == 1) ? bk : bv;
    // 0.125 = 1/sqrt(64); *1.44269504 so attn can use exp2 directly
    const float scale = (which == 0) ? 0.18033688f : 1.f;
    #pragma unroll
    for (int j = 0; j < 4; j++) {
        const int c = (n0 & 511) + wn + j * 16 + l15;
        const float bvv = bias[c];
        #pragma unroll
        for (int i = 0; i < 4; i++) {
            const int rbase = m0 + wm + i * 16 + quad * 4;
            #pragma unroll
            for (int r = 0; r < 4; r++) {
                float v = (acc[i][j][r] + bvv) * scale;
                const int row = rbase + r;
                if (which == 0)      qb[(size_t)row * DM + c] = (bf16)v;
                else if (which == 1) kb[(size_t)row * DM + c] = (bf16)v;
                else {
                    const int n = row >> 11, s = row & (SQ - 1);
                    const int h = c >> 6, hd = c & 63;
                    vtb[((size_t)(((n << 3) | h) << 6 | hd) << 11) | s] = (bf16)v;
                }
            }
        }
    }
}

// ---------------------------------------------------------------------------
// Flash attention (R4 structure). Block: one (n,h), 128 q-rows (4 waves).
// S^T = K·Q^T (16x16x32): lane holds q=l15, kv=quad*4+r == K=16 PV A-layout;
// P stays in registers. Vt stride 68 (conflict-free b64), Kt stride 72.
// Double-buffered, 1 sync/iter. (256,4): 4 blocks/CU.
// ---------------------------------------------------------------------------
__global__ __launch_bounds__(256, 4) void attn_kernel(
    const bf16* __restrict__ qb, const bf16* __restrict__ kb,
    const bf16* __restrict__ vtb, bf16* __restrict__ yb)
{
    __shared__ alignas(16) bf16 Kt[2][64][72];
    __shared__ alignas(16) bf16 Vt[2 * 64 * 68];
    const int tid = threadIdx.x;
    const int w = tid >> 6, lane = tid & 63;
    const int l15 = lane & 15, quad = lane >> 4;
    // XCD-aware decode: all 16 q-blocks of one (n,h) land on one XCD
    const int id = blockIdx.x;
    const int nh = (id & 7) * 4 + ((id >> 3) & 3);
    const int qblk = id >> 5;
    const int n = nh >> 3, h = nh & 7;
    const int q0 = qblk * 128 + w * 32;
    const bf16* qbase = qb + (size_t)n * SQ * DM + h * HD;
    const bf16* kbase = kb + (size_t)n * SQ * DM + h * HD;
    const bf16* vbase = vtb + (size_t)nh * HD * SQ;

    // Q fragments (B-operand of S^T: n=q=l15, k=d=quad*8+j)
    bf16x8 qf[2][2];
    for (int mi = 0; mi < 2; mi++)
        for (int hh = 0; hh < 2; hh++)
            qf[mi][hh] = *(const bf16x8*)(qbase + (size_t)(q0 + mi*16 + l15) * DM + hh*32 + quad*8);

    f32x4 o[2][4] = {};
    float lsum[2] = {0.f, 0.f};

    // staging: thread covers (srow, seg..seg+16) of the 64x64 tile
    const int srow = tid >> 2, seg = (tid & 3) * 16;
    const bf16* krow = kbase + (size_t)srow * DM + seg;  // K rows = kv
    const bf16* vrow = vbase + (size_t)srow * SQ + seg;  // V rows = hd

    auto storeV = [&](int buf, bf16x8 a, bf16x8 b) {
        bf16* d = &Vt[(buf * 64 + srow) * 68 + seg];
        bf16x4 p0, p1, p2, p3;
        #pragma unroll
        for (int i = 0; i < 4; i++) { p0[i]=a[i]; p1[i]=a[i+4]; p2[i]=b[i]; p3[i]=b[i+4]; }
        *(bf16x4*)(d)      = p0;
        *(bf16x4*)(d + 4)  = p1;
        *(bf16x4*)(d + 8)  = p2;
        *(bf16x4*)(d + 12) = p3;
    };

    { // prologue: stage tile 0
        bf16x8 k0 = *(const bf16x8*)(krow);
        bf16x8 k1 = *(const bf16x8*)(krow + 8);
        bf16x8 v0 = *(const bf16x8*)(vrow);
        bf16x8 v1 = *(const bf16x8*)(vrow + 8);
        *(bf16x8*)&Kt[0][srow][seg]     = k0;
        *(bf16x8*)&Kt[0][srow][seg + 8] = k1;
        storeV(0, v0, v1);
    }

    for (int jt = 0; jt < SQ / 64; jt++) {
        const int buf = jt & 1;
        __syncthreads();   // buf writes visible; prev iter's reads complete
        const bool pre = (jt + 1 < SQ / 64);
        bf16x8 k0, k1, v0, v1;
        if (pre) {         // next tile's global loads issued early
            const bf16* kp = krow + (size_t)(jt + 1) * 64 * DM;
            const bf16* vp = vrow + (jt + 1) * 64;
            k0 = *(const bf16x8*)(kp);
            k1 = *(const bf16x8*)(kp + 8);
            v0 = *(const bf16x8*)(vp);
            v1 = *(const bf16x8*)(vp + 8);
        }

        #pragma unroll
        for (int s4 = 0; s4 < 4; s4++) {
            // K A-frag (m=kv), Q B-frag -> S^T[kv][q]
            bf16x8 kf0 = *(const bf16x8*)&Kt[buf][s4*16 + l15][quad*8];
            bf16x8 kf1 = *(const bf16x8*)&Kt[buf][s4*16 + l15][32 + quad*8];
            bf16x4 pf[2];
            #pragma unroll
            for (int mi = 0; mi < 2; mi++) {
                f32x4 sacc = {};
                sacc = MFMA16(kf0, qf[mi][0], sacc);
                sacc = MFMA16(kf1, qf[mi][1], sacc);
                float p0 = fast_exp2(sacc[0]);
                float p1 = fast_exp2(sacc[1]);
                float p2 = fast_exp2(sacc[2]);
                float p3 = fast_exp2(sacc[3]);
                lsum[mi] += (p0 + p1) + (p2 + p3);
                bf16x4 pk;
                pk[0] = (bf16)p0; pk[1] = (bf16)p1;
                pk[2] = (bf16)p2; pk[3] = (bf16)p3;
                pf[mi] = pk;       // == K=16 A-frag: q=l15, kv=quad*4+j
            }
            // O[q][hd] += P V  (K=16 per s4 chunk)
            #pragma unroll
            for (int d4 = 0; d4 < 4; d4++) {
                bf16x4 vf = *(const bf16x4*)&Vt[(buf*64 + d4*16 + l15) * 68 + s4*16 + quad*4];
                o[0][d4] = mfma_k16(pf[0], vf, o[0][d4]);
                o[1][d4] = mfma_k16(pf[1], vf, o[1][d4]);
            }
        }

        if (pre) {
            *(bf16x8*)&Kt[buf^1][srow][seg]     = k0;
            *(bf16x8*)&Kt[buf^1][srow][seg + 8] = k1;
            storeV(buf^1, v0, v1);
        }
    }

    // lsum lives at q=l15 per quad; reduce across quads
    #pragma unroll
    for (int mi = 0; mi < 2; mi++) {
        lsum[mi] += __shfl_xor(lsum[mi], 16, 64);
        lsum[mi] += __shfl_xor(lsum[mi], 32, 64);
    }
    // O rows are q=quad*4+r -> fetch 1/lsum via shuffle from lane q
    #pragma unroll
    for (int mi = 0; mi < 2; mi++) {
        f32x4 rl;
        #pragma unroll
        for (int r = 0; r < 4; r++)
            rl[r] = 1.f / __shfl(lsum[mi], quad * 4 + r, 64);
        #pragma unroll
        for (int d4 = 0; d4 < 4; d4++) {
            const int col = h * HD + d4 * 16 + l15;
            #pragma unroll
            for (int r = 0; r < 4; r++) {
                const int row = n * SQ + q0 + mi*16 + quad*4 + r;
                yb[(size_t)row * DM + col] = (bf16)(o[mi][d4][r] * rl[r]);
            }
        }
    }
}

// ---------------------------------------------------------------------------
// Residual + LayerNorm: out = LN(res + add) * g + beta. One wave per row.
// ---------------------------------------------------------------------------
__global__ __launch_bounds__(256) void ln_kernel(
    const float* __restrict__ res, const float* __restrict__ add,
    const float* __restrict__ g, const float* __restrict__ beta,
    float* __restrict__ outf, bf16* __restrict__ outb)
{
    const int w = threadIdx.x >> 6, lane = threadIdx.x & 63;
    const size_t row = (size_t)blockIdx.x * 4 + w;
    const float4* rp = (const float4*)(res + row * DM);
    const float4* ap = (const float4*)(add + row * DM);
    float4 v[2];
    float s = 0.f, s2 = 0.f;
    #pragma unroll
    for (int i = 0; i < 2; i++) {
        const int idx = i * 64 + lane;
        float4 a = rp[idx], c = ap[idx];
        float x0 = a.x + c.x, x1 = a.y + c.y, x2 = a.z + c.z, x3 = a.w + c.w;
        v[i] = make_float4(x0, x1, x2, x3);
        s  += x0 + x1 + x2 + x3;
        s2 += x0*x0 + x1*x1 + x2*x2 + x3*x3;
    }
    for (int m = 1; m < 64; m <<= 1) {
        s  += __shfl_xor(s,  m, 64);
        s2 += __shfl_xor(s2, m, 64);
    }
    const float mean = s * (1.f / DM);
    const float var  = s2 * (1.f / DM) - mean * mean;
    const float rstd = rsqrtf(var + 1e-5f);
    #pragma unroll
    for (int i = 0; i < 2; i++) {
        const int idx = i * 64 + lane;
        float4 gw = ((const float4*)g)[idx], bw = ((const float4*)beta)[idx];
        float o0 = (v[i].x - mean) * rstd * gw.x + bw.x;
        float o1 = (v[i].y - mean) * rstd * gw.y + bw.y;
        float o2 = (v[i].z - mean) * rstd * gw.z + bw.z;
        float o3 = (v[i].w - mean) * rstd * gw.w + bw.w;
        ((float4*)(outf + row * DM))[idx] = make_float4(o0, o1, o2, o3);
        union { bf16 h[4]; uint2 u; } pk;
        pk.h[0] = (bf16)o0; pk.h[1] = (bf16)o1; pk.h[2] = (bf16)o2; pk.h[3] = (bf16)o3;
        *(uint2*)(outb + row * DM + idx * 4) = pk.u;
    }
}

// ---------------------------------------------------------------------------
extern "C" void kernel_launch(void* const* d_in, const int* in_sizes, int n_in,
                              void* d_out, int out_size, void* d_ws, size_t ws_size,
                              hipStream_t stream)
{
    const float* features = (const float*)d_in[0];
    const float* Wq  = (const float*)d_in[1];
    const float* bq  = (const float*)d_in[2];
    const float* Wk  = (const float*)d_in[3];
    const float* bk  = (const float*)d_in[4];
    const float* Wv  = (const float*)d_in[5];
    const float* bv  = (const float*)d_in[6];
    const float* Wo  = (const float*)d_in[7];
    const float* bo  = (const float*)d_in[8];
    const float* W1  = (const float*)d_in[9];
    const float* b1  = (const float*)d_in[10];
    const float* W2  = (const float*)d_in[11];
    const float* b2  = (const float*)d_in[12];
    const float* ln1w = (const float*)d_in[13];
    const float* ln1b = (const float*)d_in[14];
    const float* ln2w = (const float*)d_in[15];
    const float* ln2b = (const float*)d_in[16];
    float* outp = (float*)d_out;

    char* p = (char*)d_ws;
    size_t off = 0;
    auto alloc = [&](size_t bytes) { void* r = p + off; off = (off + bytes + 255) & ~(size_t)255; return r; };
    const size_t tokD = (size_t)MTOK * DM;
    float* x     = (float*)alloc(tokD * 4);
    float* tmp   = (float*)alloc(tokD * 4);
    bf16* xb     = (bf16*)alloc(tokD * 2);
    bf16* qb     = (bf16*)alloc(tokD * 2);
    bf16* kb     = (bf16*)alloc(tokD * 2);
    bf16* vtb    = (bf16*)alloc(tokD * 2);
    bf16* yb     = (bf16*)alloc(tokD * 2);
    bf16* ffh    = (bf16*)alloc((size_t)MTOK * FFP * 2);
    bf16* wqkvt  = (bf16*)alloc((size_t)NL * 3 * DM * DM * 2);
    bf16* wot    = (bf16*)alloc((size_t)NL * DM * DM * 2);
    bf16* w1t    = (bf16*)alloc((size_t)NL * FFP * DM * 2);
    bf16* w2t    = (bf16*)alloc((size_t)NL * DM * FFP * 2);
    (void)ws_size; (void)in_sizes; (void)n_in; (void)out_size;

    convw_kernel<<<dim3(16, 16, NL * 6), 256, 0, stream>>>(
        Wq, Wk, Wv, Wo, W1, W2, wqkvt, wot, w1t, w2t);

    posenc_kernel<<<MTOK, 256, 0, stream>>>(features, x, xb);

    for (int l = 0; l < NL; l++) {
        const bf16* wqkvt_l = wqkvt + (size_t)l * 3 * DM * DM;
        gemm128_qkv_kernel<<<dim3(MTOK / 128, 1536 / 128), 256, 0, stream>>>(
            xb, wqkvt_l, bq + l*DM, bk + l*DM, bv + l*DM, qb, kb, vtb);
        attn_kernel<<<512, 256, 0, stream>>>(qb, kb, vtb, yb);
        gemm128_kernel<<<dim3(MTOK / 128, DM / 128), 256, 0, stream>>>(
            yb, wot + (size_t)l*DM*DM, bo + l*DM, DM, tmp, nullptr, DM, DM, 0);
        ln_kernel<<<MTOK / 4, 256, 0, stream>>>(x, tmp, ln1w + l*DM, ln1b + l*DM, x, xb);
        gemm128_kernel<<<dim3(MTOK / 128, FFP / 128), 256, 0, stream>>>(
            xb, w1t + (size_t)l*FFP*DM, b1 + l*FF, FF, nullptr, ffh, DM, FFP, 2);
        gemm128_kernel<<<dim3(MTOK / 128, DM / 128), 256, 0, stream>>>(
            ffh, w2t + (size_t)l*DM*FFP, b2 + l*DM, DM, tmp, nullptr, FFP, DM, 0);
        float* outdst = (l == NL - 1) ? outp : x;
        ln_kernel<<<MTOK / 4, 256, 0, stream>>>(x, tmp, ln2w + l*DM, ln2b + l*DM, outdst, xb);
    }
}

// Round 6
// 681.281 us; speedup vs baseline: 1.1018x; 1.0804x over previous
//
#include <hip/hip_runtime.h>
#include <hip/hip_bf16.h>
#include <cstdint>

// ---------------------------------------------------------------------------
// ImageEncoder: 4-layer transformer encoder, N=4 S=2048 D=512 H=8 HD=64 F=200.
// fp32 residual stream + bf16 MFMA.
// R6: attn occupancy was grid-capped (512 blocks = 2/CU); (256,4) only cut
// VGPRs (72->64) killing the prefetch regs. Now: kv-split 2-way -> grid 1024
// (exactly 4 blocks/CU), unnormalized bf16 O partials + fp32 lsum partials,
// light combine kernel. attn back to (256,2) register budget.
// ---------------------------------------------------------------------------

typedef __bf16 bf16;
typedef __bf16 bf16x8 __attribute__((ext_vector_type(8)));
typedef __bf16 bf16x4 __attribute__((ext_vector_type(4)));
typedef short short4v __attribute__((ext_vector_type(4)));
typedef float f32x4 __attribute__((ext_vector_type(4)));

#define MFMA16(a, b, c) __builtin_amdgcn_mfma_f32_16x16x32_bf16((a), (b), (c), 0, 0, 0)

// K=16 MFMA: lane holds A[m=l15][k=quad*4+j]
__device__ __forceinline__ f32x4 mfma_k16(bf16x4 a, bf16x4 b, f32x4 c) {
#if __has_builtin(__builtin_amdgcn_mfma_f32_16x16x16_bf16)
    return __builtin_amdgcn_mfma_f32_16x16x16_bf16(a, b, c, 0, 0, 0);
#else
    short4v as, bs;
    __builtin_memcpy(&as, &a, 8);
    __builtin_memcpy(&bs, &b, 8);
    return __builtin_amdgcn_mfma_f32_16x16x16bf16_1k(as, bs, c, 0, 0, 0);
#endif
}

static constexpr int NB   = 4;
static constexpr int SQ   = 2048;
static constexpr int DM   = 512;
static constexpr int NH   = 8;
static constexpr int HD   = 64;
static constexpr int NL   = 4;
static constexpr int FF   = 200;
static constexpr int FFP  = 256;
static constexpr int MTOK = NB * SQ; // 8192

__device__ __forceinline__ float fast_exp2(float x) {
#if __has_builtin(__builtin_amdgcn_exp2f)
    return __builtin_amdgcn_exp2f(x);
#else
    return exp2f(x);
#endif
}

// async global->LDS, 16 bytes per lane
__device__ __forceinline__ void gld16(bf16* l, const bf16* g) {
    __builtin_amdgcn_global_load_lds(
        (const __attribute__((address_space(1))) void*)g,
        (__attribute__((address_space(3))) void*)l, 16, 0, 0);
}

// ---------------------------------------------------------------------------
// Weight convert + transpose:  src fp32 [K, Nsrc]  ->  dst bf16 [Npad, Kpad]
// ---------------------------------------------------------------------------
__global__ __launch_bounds__(256) void convw_kernel(
    const float* __restrict__ Wq, const float* __restrict__ Wk,
    const float* __restrict__ Wv, const float* __restrict__ Wo,
    const float* __restrict__ W1, const float* __restrict__ W2,
    bf16* __restrict__ wqkvt, bf16* __restrict__ wot,
    bf16* __restrict__ w1t, bf16* __restrict__ w2t)
{
    __shared__ float tile[32][33];
    const int z = blockIdx.z, l = z / 6, which = z % 6;
    const float* src; bf16* dst; int K, Nsrc, Npad, Kpad;
    switch (which) {
        case 0: src = Wq + (size_t)l*DM*DM; dst = wqkvt + (size_t)(l*3+0)*DM*DM; K=DM; Nsrc=DM; Npad=DM; Kpad=DM; break;
        case 1: src = Wk + (size_t)l*DM*DM; dst = wqkvt + (size_t)(l*3+1)*DM*DM; K=DM; Nsrc=DM; Npad=DM; Kpad=DM; break;
        case 2: src = Wv + (size_t)l*DM*DM; dst = wqkvt + (size_t)(l*3+2)*DM*DM; K=DM; Nsrc=DM; Npad=DM; Kpad=DM; break;
        case 3: src = Wo + (size_t)l*DM*DM; dst = wot   + (size_t)l*DM*DM;       K=DM; Nsrc=DM; Npad=DM; Kpad=DM; break;
        case 4: src = W1 + (size_t)l*DM*FF; dst = w1t   + (size_t)l*FFP*DM;      K=DM; Nsrc=FF; Npad=FFP; Kpad=DM; break;
        default:src = W2 + (size_t)l*FF*DM; dst = w2t   + (size_t)l*DM*FFP;      K=FF; Nsrc=DM; Npad=DM; Kpad=FFP; break;
    }
    const int k0 = blockIdx.x * 32, n0 = blockIdx.y * 32;
    if (k0 >= Kpad || n0 >= Npad) return;
    const int tr = threadIdx.x >> 3, tc = (threadIdx.x & 7) * 4;
    for (int c = 0; c < 4; c++) {
        int sr = k0 + tr, sc = n0 + tc + c;
        tile[tr][tc + c] = (sr < K && sc < Nsrc) ? src[(size_t)sr * Nsrc + sc] : 0.f;
    }
    __syncthreads();
    const int dr = n0 + tr;
    if (dr < Npad) {
        for (int c = 0; c < 4; c++) {
            int dc = k0 + tc + c;
            if (dc < Kpad) dst[(size_t)dr * Kpad + dc] = (bf16)tile[tc + c][tr];
        }
    }
}

// ---------------------------------------------------------------------------
// Positional encoding add + cast
// ---------------------------------------------------------------------------
__global__ __launch_bounds__(256) void posenc_kernel(
    const float* __restrict__ f, float* __restrict__ x, bf16* __restrict__ xb)
{
    const int t = blockIdx.x * 256 + threadIdx.x;
    const int d2 = t & 255, row = t >> 8, s = row & (SQ - 1);
    const float kfac = -0.03597789207803197f;           // -2*ln(10000)/512
    float dv = __expf((float)d2 * kfac);
    float ang = (float)s * dv;
    float pe0 = sinf(ang), pe1 = cosf(ang);
    const size_t base = (size_t)row * DM + d2 * 2;
    float2 fv = *(const float2*)(f + base);
    float o0 = fv.x + pe0, o1 = fv.y + pe1;
    *(float2*)(x + base) = make_float2(o0, o1);
    union { bf16 h[2]; unsigned int u; } pk;
    pk.h[0] = (bf16)o0; pk.h[1] = (bf16)o1;
    *(unsigned int*)(xb + base) = pk.u;
}

// ---------------------------------------------------------------------------
// m97-style GEMM core: block tile 128x128, BK=32, 4 waves (2x2 of 64x64).
// ---------------------------------------------------------------------------
__device__ __forceinline__ void gemm128_core(
    const bf16* __restrict__ A, const bf16* __restrict__ Wt, int K,
    int m0, int n0, bf16* As, bf16* Bs, f32x4 (&acc)[4][4])
{
    const int tid = threadIdx.x;
    const int w = tid >> 6, lane = tid & 63;
    const int l15 = lane & 15, quad = lane >> 4;
    const int srow = w * 16 + (lane >> 2);
    const int scol = (lane & 3) * 8;
    const bf16* Ag = A  + (size_t)(m0 + srow) * K + scol;
    const bf16* Bg = Wt + (size_t)(n0 + srow) * K + scol;
    bf16* AsW = As + w * 512;
    bf16* BsW = Bs + w * 512;
    const int wm = (w >> 1) * 64, wn = (w & 1) * 64;

    for (int k0 = 0; k0 < K; k0 += 32) {
        __syncthreads();
        gld16(AsW,        Ag + k0);
        gld16(AsW + 2048, Ag + (size_t)64 * K + k0);
        gld16(BsW,        Bg + k0);
        gld16(BsW + 2048, Bg + (size_t)64 * K + k0);
        asm volatile("s_waitcnt vmcnt(0)" ::: "memory");
        __syncthreads();

        bf16x8 af[4], bfr[4];
        #pragma unroll
        for (int i = 0; i < 4; i++)
            af[i] = *(const bf16x8*)&As[(wm + i * 16 + l15) * 32 + quad * 8];
        #pragma unroll
        for (int j = 0; j < 4; j++)
            bfr[j] = *(const bf16x8*)&Bs[(wn + j * 16 + l15) * 32 + quad * 8];
        #pragma unroll
        for (int i = 0; i < 4; i++)
            #pragma unroll
            for (int j = 0; j < 4; j++)
                acc[i][j] = MFMA16(af[i], bfr[j], acc[i][j]);
    }
}

// modes: 0 fp32 out, 1 bf16 out, 2 bf16 relu
__global__ __launch_bounds__(256, 3) void gemm128_kernel(
    const bf16* __restrict__ A, const bf16* __restrict__ Wt,
    const float* __restrict__ bias, int nbias,
    float* __restrict__ outf, bf16* __restrict__ outb,
    int K, int Nc, int mode)
{
    __shared__ alignas(16) bf16 As[128 * 32];
    __shared__ alignas(16) bf16 Bs[128 * 32];
    const int m0 = blockIdx.x * 128, n0 = blockIdx.y * 128;
    f32x4 acc[4][4] = {};
    gemm128_core(A, Wt, K, m0, n0, As, Bs, acc);

    const int lane = threadIdx.x & 63;
    const int l15 = lane & 15, quad = lane >> 4;
    const int w = threadIdx.x >> 6;
    const int wm = (w >> 1) * 64, wn = (w & 1) * 64;
    #pragma unroll
    for (int j = 0; j < 4; j++) {
        const int col = n0 + wn + j * 16 + l15;
        const float bv = (col < nbias) ? bias[col] : 0.f;
        #pragma unroll
        for (int i = 0; i < 4; i++) {
            const int rbase = m0 + wm + i * 16 + quad * 4;
            #pragma unroll
            for (int r = 0; r < 4; r++) {
                float v = acc[i][j][r] + bv;
                const int row = rbase + r;
                const size_t idx = (size_t)row * Nc + col;
                if (mode == 0)      outf[idx] = v;
                else if (mode == 1) outb[idx] = (bf16)v;
                else                outb[idx] = (bf16)fmaxf(v, 0.f);
            }
        }
    }
}

// fused QKV. Q gets (1/sqrt(HD))*log2(e) folded in (softmax uses exp2);
// V written transposed to [n,h,hd,s].
__global__ __launch_bounds__(256, 3) void gemm128_qkv_kernel(
    const bf16* __restrict__ xb, const bf16* __restrict__ Wt,
    const float* __restrict__ bq, const float* __restrict__ bk,
    const float* __restrict__ bv,
    bf16* __restrict__ qb, bf16* __restrict__ kb, bf16* __restrict__ vtb)
{
    __shared__ alignas(16) bf16 As[128 * 32];
    __shared__ alignas(16) bf16 Bs[128 * 32];
    const int m0 = blockIdx.x * 128, n0 = blockIdx.y * 128;
    f32x4 acc[4][4] = {};
    gemm128_core(xb, Wt, DM, m0, n0, As, Bs, acc);

    const int lane = threadIdx.x & 63;
    const int l15 = lane & 15, quad = lane >> 4;
    const int w = threadIdx.x >> 6;
    const int wm = (w >> 1) * 64, wn = (w & 1) * 64;
    const int which = n0 >> 9;
    const float* bias = (which == 0) ? bq : (which == 1) ? bk : bv;
    // 0.125 = 1/sqrt(64); *1.44269504 so attn can use exp2 directly
    const float scale = (which == 0) ? 0.18033688f : 1.f;
    #pragma unroll
    for (int j = 0; j < 4; j++) {
        const int c = (n0 & 511) + wn + j * 16 + l15;
        const float bvv = bias[c];
        #pragma unroll
        for (int i = 0; i < 4; i++) {
            const int rbase = m0 + wm + i * 16 + quad * 4;
            #pragma unroll
            for (int r = 0; r < 4; r++) {
                float v = (acc[i][j][r] + bvv) * scale;
                const int row = rbase + r;
                if (which == 0)      qb[(size_t)row * DM + c] = (bf16)v;
                else if (which == 1) kb[(size_t)row * DM + c] = (bf16)v;
                else {
                    const int n = row >> 11, s = row & (SQ - 1);
                    const int h = c >> 6, hd = c & 63;
                    vtb[((size_t)(((n << 3) | h) << 6 | hd) << 11) | s] = (bf16)v;
                }
            }
        }
    }
}

// ---------------------------------------------------------------------------
// Flash attention, R6: kv-split 2-way. Block: one (n,h,kvhalf), 128 q-rows
// (4 waves x 32 q), 16 kv-tiles of 64. Grid 1024 = 4 blocks/CU.
// S^T = K·Q^T: lane holds q=l15, kv=quad*4+r == K=16 PV A-layout (reg-P).
// Writes UNNORMALIZED O (bf16) + lsum (fp32) partials; combine kernel divides.
// id bits: kvhalf=id&1, nh=(id>>1)&31, qblk=id>>6 -> id%8 fixed per
// (nh,kvhalf): all 16 q-blocks of one partial share an XCD.
// ---------------------------------------------------------------------------
__global__ __launch_bounds__(256, 2) void attn_kernel(
    const bf16* __restrict__ qb, const bf16* __restrict__ kb,
    const bf16* __restrict__ vtb,
    bf16* __restrict__ opart0, bf16* __restrict__ opart1,
    float* __restrict__ lpart)
{
    __shared__ alignas(16) bf16 Kt[2][64][72];
    __shared__ alignas(16) bf16 Vt[2 * 64 * 68];
    const int tid = threadIdx.x;
    const int w = tid >> 6, lane = tid & 63;
    const int l15 = lane & 15, quad = lane >> 4;
    const int id = blockIdx.x;
    const int kvhalf = id & 1;
    const int nh = (id >> 1) & 31;
    const int qblk = id >> 6;
    const int n = nh >> 3, h = nh & 7;
    const int q0 = qblk * 128 + w * 32;
    const int kvbase = kvhalf * (SQ / 2);
    const bf16* qbase = qb + (size_t)n * SQ * DM + h * HD;
    const bf16* kbase = kb + (size_t)n * SQ * DM + h * HD;
    const bf16* vbase = vtb + (size_t)nh * HD * SQ;

    // Q fragments (B-operand of S^T: n=q=l15, k=d=quad*8+j)
    bf16x8 qf[2][2];
    for (int mi = 0; mi < 2; mi++)
        for (int hh = 0; hh < 2; hh++)
            qf[mi][hh] = *(const bf16x8*)(qbase + (size_t)(q0 + mi*16 + l15) * DM + hh*32 + quad*8);

    f32x4 o[2][4] = {};
    float lsum[2] = {0.f, 0.f};

    // staging: thread covers (srow, seg..seg+16) of the 64x64 tile
    const int srow = tid >> 2, seg = (tid & 3) * 16;
    const bf16* krow = kbase + (size_t)(kvbase + srow) * DM + seg;  // K rows = kv
    const bf16* vrow = vbase + (size_t)srow * SQ + kvbase + seg;    // V rows = hd

    auto storeV = [&](int buf, bf16x8 a, bf16x8 b) {
        bf16* d = &Vt[(buf * 64 + srow) * 68 + seg];
        bf16x4 p0, p1, p2, p3;
        #pragma unroll
        for (int i = 0; i < 4; i++) { p0[i]=a[i]; p1[i]=a[i+4]; p2[i]=b[i]; p3[i]=b[i+4]; }
        *(bf16x4*)(d)      = p0;
        *(bf16x4*)(d + 4)  = p1;
        *(bf16x4*)(d + 8)  = p2;
        *(bf16x4*)(d + 12) = p3;
    };

    { // prologue: stage tile 0 of this half
        bf16x8 k0 = *(const bf16x8*)(krow);
        bf16x8 k1 = *(const bf16x8*)(krow + 8);
        bf16x8 v0 = *(const bf16x8*)(vrow);
        bf16x8 v1 = *(const bf16x8*)(vrow + 8);
        *(bf16x8*)&Kt[0][srow][seg]     = k0;
        *(bf16x8*)&Kt[0][srow][seg + 8] = k1;
        storeV(0, v0, v1);
    }

    const int NT = SQ / 128;   // 16 tiles per half
    for (int jt = 0; jt < NT; jt++) {
        const int buf = jt & 1;
        __syncthreads();   // buf writes visible; prev iter's reads complete
        const bool pre = (jt + 1 < NT);
        bf16x8 k0, k1, v0, v1;
        if (pre) {         // next tile's global loads issued early
            const bf16* kp = krow + (size_t)(jt + 1) * 64 * DM;
            const bf16* vp = vrow + (jt + 1) * 64;
            k0 = *(const bf16x8*)(kp);
            k1 = *(const bf16x8*)(kp + 8);
            v0 = *(const bf16x8*)(vp);
            v1 = *(const bf16x8*)(vp + 8);
        }

        #pragma unroll
        for (int s4 = 0; s4 < 4; s4++) {
            // K A-frag (m=kv), Q B-frag -> S^T[kv][q]
            bf16x8 kf0 = *(const bf16x8*)&Kt[buf][s4*16 + l15][quad*8];
            bf16x8 kf1 = *(const bf16x8*)&Kt[buf][s4*16 + l15][32 + quad*8];
            bf16x4 pf[2];
            #pragma unroll
            for (int mi = 0; mi < 2; mi++) {
                f32x4 sacc = {};
                sacc = MFMA16(kf0, qf[mi][0], sacc);
                sacc = MFMA16(kf1, qf[mi][1], sacc);
                float p0 = fast_exp2(sacc[0]);
                float p1 = fast_exp2(sacc[1]);
                float p2 = fast_exp2(sacc[2]);
                float p3 = fast_exp2(sacc[3]);
                lsum[mi] += (p0 + p1) + (p2 + p3);
                bf16x4 pk;
                pk[0] = (bf16)p0; pk[1] = (bf16)p1;
                pk[2] = (bf16)p2; pk[3] = (bf16)p3;
                pf[mi] = pk;       // == K=16 A-frag: q=l15, kv=quad*4+j
            }
            // O[q][hd] += P V  (K=16 per s4 chunk)
            #pragma unroll
            for (int d4 = 0; d4 < 4; d4++) {
                bf16x4 vf = *(const bf16x4*)&Vt[(buf*64 + d4*16 + l15) * 68 + s4*16 + quad*4];
                o[0][d4] = mfma_k16(pf[0], vf, o[0][d4]);
                o[1][d4] = mfma_k16(pf[1], vf, o[1][d4]);
            }
        }

        if (pre) {
            *(bf16x8*)&Kt[buf^1][srow][seg]     = k0;
            *(bf16x8*)&Kt[buf^1][srow][seg + 8] = k1;
            storeV(buf^1, v0, v1);
        }
    }

    // lsum lives at q=l15 per quad; reduce across quads, write fp32 partials
    #pragma unroll
    for (int mi = 0; mi < 2; mi++) {
        lsum[mi] += __shfl_xor(lsum[mi], 16, 64);
        lsum[mi] += __shfl_xor(lsum[mi], 32, 64);
    }
    if (lane < 16) {
        const int qg = (nh << 11) + q0 + lane;   // nh*2048 + q
        lpart[(kvhalf << 16) + qg]      = lsum[0];
        lpart[(kvhalf << 16) + qg + 16] = lsum[1];
    }

    // write unnormalized O partial (bf16)
    bf16* op = kvhalf ? opart1 : opart0;
    #pragma unroll
    for (int mi = 0; mi < 2; mi++) {
        #pragma unroll
        for (int d4 = 0; d4 < 4; d4++) {
            const int col = h * HD + d4 * 16 + l15;
            #pragma unroll
            for (int r = 0; r < 4; r++) {
                const int row = n * SQ + q0 + mi*16 + quad*4 + r;
                op[(size_t)row * DM + col] = (bf16)o[mi][d4][r];
            }
        }
    }
}

// combine: yb = (O0 + O1) / (l0 + l1).  yb may alias o0 (same-thread RMW).
__global__ __launch_bounds__(256) void attn_combine_kernel(
    const bf16* o0, const bf16* o1, const float* __restrict__ lpart,
    bf16* yb)
{
    const int w = threadIdx.x >> 6, lane = threadIdx.x & 63;
    const size_t row = (size_t)blockIdx.x * 4 + w;
    const int q = (int)(row & (SQ - 1));
    const int nh = (int)(row >> 11) * 8 + (lane >> 3);
    const float rl = 1.f / (lpart[(nh << 11) + q] + lpart[(1 << 16) + (nh << 11) + q]);
    const size_t base = row * DM + lane * 8;
    bf16x8 a = *(const bf16x8*)(o0 + base);
    bf16x8 b = *(const bf16x8*)(o1 + base);
    bf16x8 y;
    #pragma unroll
    for (int i = 0; i < 8; i++)
        y[i] = (bf16)(((float)a[i] + (float)b[i]) * rl);
    *(bf16x8*)(yb + base) = y;
}

// ---------------------------------------------------------------------------
// Residual + LayerNorm: out = LN(res + add) * g + beta. One wave per row.
// ---------------------------------------------------------------------------
__global__ __launch_bounds__(256) void ln_kernel(
    const float* __restrict__ res, const float* __restrict__ add,
    const float* __restrict__ g, const float* __restrict__ beta,
    float* __restrict__ outf, bf16* __restrict__ outb)
{
    const int w = threadIdx.x >> 6, lane = threadIdx.x & 63;
    const size_t row = (size_t)blockIdx.x * 4 + w;
    const float4* rp = (const float4*)(res + row * DM);
    const float4* ap = (const float4*)(add + row * DM);
    float4 v[2];
    float s = 0.f, s2 = 0.f;
    #pragma unroll
    for (int i = 0; i < 2; i++) {
        const int idx = i * 64 + lane;
        float4 a = rp[idx], c = ap[idx];
        float x0 = a.x + c.x, x1 = a.y + c.y, x2 = a.z + c.z, x3 = a.w + c.w;
        v[i] = make_float4(x0, x1, x2, x3);
        s  += x0 + x1 + x2 + x3;
        s2 += x0*x0 + x1*x1 + x2*x2 + x3*x3;
    }
    for (int m = 1; m < 64; m <<= 1) {
        s  += __shfl_xor(s,  m, 64);
        s2 += __shfl_xor(s2, m, 64);
    }
    const float mean = s * (1.f / DM);
    const float var  = s2 * (1.f / DM) - mean * mean;
    const float rstd = rsqrtf(var + 1e-5f);
    #pragma unroll
    for (int i = 0; i < 2; i++) {
        const int idx = i * 64 + lane;
        float4 gw = ((const float4*)g)[idx], bw = ((const float4*)beta)[idx];
        float o0 = (v[i].x - mean) * rstd * gw.x + bw.x;
        float o1 = (v[i].y - mean) * rstd * gw.y + bw.y;
        float o2 = (v[i].z - mean) * rstd * gw.z + bw.z;
        float o3 = (v[i].w - mean) * rstd * gw.w + bw.w;
        ((float4*)(outf + row * DM))[idx] = make_float4(o0, o1, o2, o3);
        union { bf16 h[4]; uint2 u; } pk;
        pk.h[0] = (bf16)o0; pk.h[1] = (bf16)o1; pk.h[2] = (bf16)o2; pk.h[3] = (bf16)o3;
        *(uint2*)(outb + row * DM + idx * 4) = pk.u;
    }
}

// ---------------------------------------------------------------------------
extern "C" void kernel_launch(void* const* d_in, const int* in_sizes, int n_in,
                              void* d_out, int out_size, void* d_ws, size_t ws_size,
                              hipStream_t stream)
{
    const float* features = (const float*)d_in[0];
    const float* Wq  = (const float*)d_in[1];
    const float* bq  = (const float*)d_in[2];
    const float* Wk  = (const float*)d_in[3];
    const float* bk  = (const float*)d_in[4];
    const float* Wv  = (const float*)d_in[5];
    const float* bv  = (const float*)d_in[6];
    const float* Wo  = (const float*)d_in[7];
    const float* bo  = (const float*)d_in[8];
    const float* W1  = (const float*)d_in[9];
    const float* b1  = (const float*)d_in[10];
    const float* W2  = (const float*)d_in[11];
    const float* b2  = (const float*)d_in[12];
    const float* ln1w = (const float*)d_in[13];
    const float* ln1b = (const float*)d_in[14];
    const float* ln2w = (const float*)d_in[15];
    const float* ln2b = (const float*)d_in[16];
    float* outp = (float*)d_out;

    char* p = (char*)d_ws;
    size_t off = 0;
    auto alloc = [&](size_t bytes) { void* r = p + off; off = (off + bytes + 255) & ~(size_t)255; return r; };
    const size_t tokD = (size_t)MTOK * DM;
    float* x     = (float*)alloc(tokD * 4);
    float* tmp   = (float*)alloc(tokD * 4);
    bf16* xb     = (bf16*)alloc(tokD * 2);
    bf16* qb     = (bf16*)alloc(tokD * 2);
    bf16* kb     = (bf16*)alloc(tokD * 2);
    bf16* vtb    = (bf16*)alloc(tokD * 2);
    bf16* yb     = (bf16*)alloc(tokD * 2);   // doubles as O partial 0
    bf16* opart1 = (bf16*)alloc(tokD * 2);
    float* lpart = (float*)alloc(2 * 65536 * 4);
    bf16* ffh    = (bf16*)alloc((size_t)MTOK * FFP * 2);
    bf16* wqkvt  = (bf16*)alloc((size_t)NL * 3 * DM * DM * 2);
    bf16* wot    = (bf16*)alloc((size_t)NL * DM * DM * 2);
    bf16* w1t    = (bf16*)alloc((size_t)NL * FFP * DM * 2);
    bf16* w2t    = (bf16*)alloc((size_t)NL * DM * FFP * 2);
    (void)ws_size; (void)in_sizes; (void)n_in; (void)out_size;

    convw_kernel<<<dim3(16, 16, NL * 6), 256, 0, stream>>>(
        Wq, Wk, Wv, Wo, W1, W2, wqkvt, wot, w1t, w2t);

    posenc_kernel<<<MTOK, 256, 0, stream>>>(features, x, xb);

    for (int l = 0; l < NL; l++) {
        const bf16* wqkvt_l = wqkvt + (size_t)l * 3 * DM * DM;
        gemm128_qkv_kernel<<<dim3(MTOK / 128, 1536 / 128), 256, 0, stream>>>(
            xb, wqkvt_l, bq + l*DM, bk + l*DM, bv + l*DM, qb, kb, vtb);
        attn_kernel<<<1024, 256, 0, stream>>>(qb, kb, vtb, yb, opart1, lpart);
        attn_combine_kernel<<<MTOK / 4, 256, 0, stream>>>(yb, opart1, lpart, yb);
        gemm128_kernel<<<dim3(MTOK / 128, DM / 128), 256, 0, stream>>>(
            yb, wot + (size_t)l*DM*DM, bo + l*DM, DM, tmp, nullptr, DM, DM, 0);
        ln_kernel<<<MTOK / 4, 256, 0, stream>>>(x, tmp, ln1w + l*DM, ln1b + l*DM, x, xb);
        gemm128_kernel<<<dim3(MTOK / 128, FFP / 128), 256, 0, stream>>>(
            xb, w1t + (size_t)l*FFP*DM, b1 + l*FF, FF, nullptr, ffh, DM, FFP, 2);
        gemm128_kernel<<<dim3(MTOK / 128, DM / 128), 256, 0, stream>>>(
            ffh, w2t + (size_t)l*DM*FFP, b2 + l*DM, DM, tmp, nullptr, FFP, DM, 0);
        float* outdst = (l == NL - 1) ? outp : x;
        ln_kernel<<<MTOK / 4, 256, 0, stream>>>(x, tmp, ln2w + l*DM, ln2b + l*DM, outdst, xb);
    }
}

// Round 7
// 642.384 us; speedup vs baseline: 1.1685x; 1.0606x over previous
//
#include <hip/hip_runtime.h>
#include <hip/hip_bf16.h>
#include <cstdint>

// ---------------------------------------------------------------------------
// ImageEncoder: 4-layer transformer encoder, N=4 S=2048 D=512 H=8 HD=64 F=200.
// fp32 residual stream + bf16 MFMA.
// R7: attn is issue-bound (R6: MFMA+VALU=87%, occupancy-doubling bought 1%).
// -> q=64 per wave (block 256 q, grid 512 = 2 blocks/CU): halves per-element
// staging/kf/loop cost; each Vt read feeds 4 PV MFMAs.
// GEMM: Wo/FFN2 were 1 block/CU, FFN1 0.5! -> new 128x64-tile gemm64 kernel
// (2/CU for Wo/FFN2, 1/CU for FFN1). QKV stays on 128x128 (3/CU).
// ---------------------------------------------------------------------------

typedef __bf16 bf16;
typedef __bf16 bf16x8 __attribute__((ext_vector_type(8)));
typedef __bf16 bf16x4 __attribute__((ext_vector_type(4)));
typedef short short4v __attribute__((ext_vector_type(4)));
typedef float f32x4 __attribute__((ext_vector_type(4)));

#define MFMA16(a, b, c) __builtin_amdgcn_mfma_f32_16x16x32_bf16((a), (b), (c), 0, 0, 0)

// K=16 MFMA: lane holds A[m=l15][k=quad*4+j]
__device__ __forceinline__ f32x4 mfma_k16(bf16x4 a, bf16x4 b, f32x4 c) {
#if __has_builtin(__builtin_amdgcn_mfma_f32_16x16x16_bf16)
    return __builtin_amdgcn_mfma_f32_16x16x16_bf16(a, b, c, 0, 0, 0);
#else
    short4v as, bs;
    __builtin_memcpy(&as, &a, 8);
    __builtin_memcpy(&bs, &b, 8);
    return __builtin_amdgcn_mfma_f32_16x16x16bf16_1k(as, bs, c, 0, 0, 0);
#endif
}

static constexpr int NB   = 4;
static constexpr int SQ   = 2048;
static constexpr int DM   = 512;
static constexpr int NH   = 8;
static constexpr int HD   = 64;
static constexpr int NL   = 4;
static constexpr int FF   = 200;
static constexpr int FFP  = 256;
static constexpr int MTOK = NB * SQ; // 8192

__device__ __forceinline__ float fast_exp2(float x) {
#if __has_builtin(__builtin_amdgcn_exp2f)
    return __builtin_amdgcn_exp2f(x);
#else
    return exp2f(x);
#endif
}

// async global->LDS, 16 bytes per lane
__device__ __forceinline__ void gld16(bf16* l, const bf16* g) {
    __builtin_amdgcn_global_load_lds(
        (const __attribute__((address_space(1))) void*)g,
        (__attribute__((address_space(3))) void*)l, 16, 0, 0);
}

// ---------------------------------------------------------------------------
// Weight convert + transpose:  src fp32 [K, Nsrc]  ->  dst bf16 [Npad, Kpad]
// ---------------------------------------------------------------------------
__global__ __launch_bounds__(256) void convw_kernel(
    const float* __restrict__ Wq, const float* __restrict__ Wk,
    const float* __restrict__ Wv, const float* __restrict__ Wo,
    const float* __restrict__ W1, const float* __restrict__ W2,
    bf16* __restrict__ wqkvt, bf16* __restrict__ wot,
    bf16* __restrict__ w1t, bf16* __restrict__ w2t)
{
    __shared__ float tile[32][33];
    const int z = blockIdx.z, l = z / 6, which = z % 6;
    const float* src; bf16* dst; int K, Nsrc, Npad, Kpad;
    switch (which) {
        case 0: src = Wq + (size_t)l*DM*DM; dst = wqkvt + (size_t)(l*3+0)*DM*DM; K=DM; Nsrc=DM; Npad=DM; Kpad=DM; break;
        case 1: src = Wk + (size_t)l*DM*DM; dst = wqkvt + (size_t)(l*3+1)*DM*DM; K=DM; Nsrc=DM; Npad=DM; Kpad=DM; break;
        case 2: src = Wv + (size_t)l*DM*DM; dst = wqkvt + (size_t)(l*3+2)*DM*DM; K=DM; Nsrc=DM; Npad=DM; Kpad=DM; break;
        case 3: src = Wo + (size_t)l*DM*DM; dst = wot   + (size_t)l*DM*DM;       K=DM; Nsrc=DM; Npad=DM; Kpad=DM; break;
        case 4: src = W1 + (size_t)l*DM*FF; dst = w1t   + (size_t)l*FFP*DM;      K=DM; Nsrc=FF; Npad=FFP; Kpad=DM; break;
        default:src = W2 + (size_t)l*FF*DM; dst = w2t   + (size_t)l*DM*FFP;      K=FF; Nsrc=DM; Npad=DM; Kpad=FFP; break;
    }
    const int k0 = blockIdx.x * 32, n0 = blockIdx.y * 32;
    if (k0 >= Kpad || n0 >= Npad) return;
    const int tr = threadIdx.x >> 3, tc = (threadIdx.x & 7) * 4;
    for (int c = 0; c < 4; c++) {
        int sr = k0 + tr, sc = n0 + tc + c;
        tile[tr][tc + c] = (sr < K && sc < Nsrc) ? src[(size_t)sr * Nsrc + sc] : 0.f;
    }
    __syncthreads();
    const int dr = n0 + tr;
    if (dr < Npad) {
        for (int c = 0; c < 4; c++) {
            int dc = k0 + tc + c;
            if (dc < Kpad) dst[(size_t)dr * Kpad + dc] = (bf16)tile[tc + c][tr];
        }
    }
}

// ---------------------------------------------------------------------------
// Positional encoding add + cast
// ---------------------------------------------------------------------------
__global__ __launch_bounds__(256) void posenc_kernel(
    const float* __restrict__ f, float* __restrict__ x, bf16* __restrict__ xb)
{
    const int t = blockIdx.x * 256 + threadIdx.x;
    const int d2 = t & 255, row = t >> 8, s = row & (SQ - 1);
    const float kfac = -0.03597789207803197f;           // -2*ln(10000)/512
    float dv = __expf((float)d2 * kfac);
    float ang = (float)s * dv;
    float pe0 = sinf(ang), pe1 = cosf(ang);
    const size_t base = (size_t)row * DM + d2 * 2;
    float2 fv = *(const float2*)(f + base);
    float o0 = fv.x + pe0, o1 = fv.y + pe1;
    *(float2*)(x + base) = make_float2(o0, o1);
    union { bf16 h[2]; unsigned int u; } pk;
    pk.h[0] = (bf16)o0; pk.h[1] = (bf16)o1;
    *(unsigned int*)(xb + base) = pk.u;
}

// ---------------------------------------------------------------------------
// m97-style GEMM core: block tile 128x128, BK=32, 4 waves (2x2 of 64x64).
// ---------------------------------------------------------------------------
__device__ __forceinline__ void gemm128_core(
    const bf16* __restrict__ A, const bf16* __restrict__ Wt, int K,
    int m0, int n0, bf16* As, bf16* Bs, f32x4 (&acc)[4][4])
{
    const int tid = threadIdx.x;
    const int w = tid >> 6, lane = tid & 63;
    const int l15 = lane & 15, quad = lane >> 4;
    const int srow = w * 16 + (lane >> 2);
    const int scol = (lane & 3) * 8;
    const bf16* Ag = A  + (size_t)(m0 + srow) * K + scol;
    const bf16* Bg = Wt + (size_t)(n0 + srow) * K + scol;
    bf16* AsW = As + w * 512;
    bf16* BsW = Bs + w * 512;
    const int wm = (w >> 1) * 64, wn = (w & 1) * 64;

    for (int k0 = 0; k0 < K; k0 += 32) {
        __syncthreads();
        gld16(AsW,        Ag + k0);
        gld16(AsW + 2048, Ag + (size_t)64 * K + k0);
        gld16(BsW,        Bg + k0);
        gld16(BsW + 2048, Bg + (size_t)64 * K + k0);
        asm volatile("s_waitcnt vmcnt(0)" ::: "memory");
        __syncthreads();

        bf16x8 af[4], bfr[4];
        #pragma unroll
        for (int i = 0; i < 4; i++)
            af[i] = *(const bf16x8*)&As[(wm + i * 16 + l15) * 32 + quad * 8];
        #pragma unroll
        for (int j = 0; j < 4; j++)
            bfr[j] = *(const bf16x8*)&Bs[(wn + j * 16 + l15) * 32 + quad * 8];
        #pragma unroll
        for (int i = 0; i < 4; i++)
            #pragma unroll
            for (int j = 0; j < 4; j++)
                acc[i][j] = MFMA16(af[i], bfr[j], acc[i][j]);
    }
}

// 128x64-tile GEMM (wave-tile 64x32): for narrow-Nc GEMMs where 128x128
// grids leave CUs idle (Wo/FFN2: 512 blocks = 2/CU; FFN1: 256 = 1/CU).
// modes: 0 fp32 out, 1 bf16 out, 2 bf16 relu
__global__ __launch_bounds__(256, 3) void gemm64_kernel(
    const bf16* __restrict__ A, const bf16* __restrict__ Wt,
    const float* __restrict__ bias, int nbias,
    float* __restrict__ outf, bf16* __restrict__ outb,
    int K, int Nc, int mode)
{
    __shared__ alignas(16) bf16 As[128 * 32];
    __shared__ alignas(16) bf16 Bs[64 * 32];
    const int m0 = blockIdx.x * 128, n0 = blockIdx.y * 64;
    const int tid = threadIdx.x;
    const int w = tid >> 6, lane = tid & 63;
    const int l15 = lane & 15, quad = lane >> 4;
    const int srow = w * 16 + (lane >> 2);
    const int scol = (lane & 3) * 8;
    const bf16* Ag = A  + (size_t)(m0 + srow) * K + scol;
    const bf16* Bg = Wt + (size_t)(n0 + srow) * K + scol;
    bf16* AsW = As + w * 512;
    bf16* BsW = Bs + w * 512;
    const int wm = (w >> 1) * 64, wn = (w & 1) * 32;
    f32x4 acc[4][2] = {};

    for (int k0 = 0; k0 < K; k0 += 32) {
        __syncthreads();
        gld16(AsW,        Ag + k0);
        gld16(AsW + 2048, Ag + (size_t)64 * K + k0);
        gld16(BsW,        Bg + k0);
        asm volatile("s_waitcnt vmcnt(0)" ::: "memory");
        __syncthreads();

        bf16x8 af[4], bfr[2];
        #pragma unroll
        for (int i = 0; i < 4; i++)
            af[i] = *(const bf16x8*)&As[(wm + i * 16 + l15) * 32 + quad * 8];
        #pragma unroll
        for (int j = 0; j < 2; j++)
            bfr[j] = *(const bf16x8*)&Bs[(wn + j * 16 + l15) * 32 + quad * 8];
        #pragma unroll
        for (int i = 0; i < 4; i++)
            #pragma unroll
            for (int j = 0; j < 2; j++)
                acc[i][j] = MFMA16(af[i], bfr[j], acc[i][j]);
    }

    #pragma unroll
    for (int j = 0; j < 2; j++) {
        const int col = n0 + wn + j * 16 + l15;
        const float bv = (col < nbias) ? bias[col] : 0.f;
        #pragma unroll
        for (int i = 0; i < 4; i++) {
            const int rbase = m0 + wm + i * 16 + quad * 4;
            #pragma unroll
            for (int r = 0; r < 4; r++) {
                float v = acc[i][j][r] + bv;
                const int row = rbase + r;
                const size_t idx = (size_t)row * Nc + col;
                if (mode == 0)      outf[idx] = v;
                else if (mode == 1) outb[idx] = (bf16)v;
                else                outb[idx] = (bf16)fmaxf(v, 0.f);
            }
        }
    }
}

// fused QKV (128x128 core). Q gets (1/sqrt(HD))*log2(e) folded in;
// V written transposed to [n,h,hd,s].
__global__ __launch_bounds__(256, 3) void gemm128_qkv_kernel(
    const bf16* __restrict__ xb, const bf16* __restrict__ Wt,
    const float* __restrict__ bq, const float* __restrict__ bk,
    const float* __restrict__ bv,
    bf16* __restrict__ qb, bf16* __restrict__ kb, bf16* __restrict__ vtb)
{
    __shared__ alignas(16) bf16 As[128 * 32];
    __shared__ alignas(16) bf16 Bs[128 * 32];
    const int m0 = blockIdx.x * 128, n0 = blockIdx.y * 128;
    f32x4 acc[4][4] = {};
    gemm128_core(xb, Wt, DM, m0, n0, As, Bs, acc);

    const int lane = threadIdx.x & 63;
    const int l15 = lane & 15, quad = lane >> 4;
    const int w = threadIdx.x >> 6;
    const int wm = (w >> 1) * 64, wn = (w & 1) * 64;
    const int which = n0 >> 9;
    const float* bias = (which == 0) ? bq : (which == 1) ? bk : bv;
    // 0.125 = 1/sqrt(64); *1.44269504 so attn can use exp2 directly
    const float scale = (which == 0) ? 0.18033688f : 1.f;
    #pragma unroll
    for (int j = 0; j < 4; j++) {
        const int c = (n0 & 511) + wn + j * 16 + l15;
        const float bvv = bias[c];
        #pragma unroll
        for (int i = 0; i < 4; i++) {
            const int rbase = m0 + wm + i * 16 + quad * 4;
            #pragma unroll
            for (int r = 0; r < 4; r++) {
                float v = (acc[i][j][r] + bvv) * scale;
                const int row = rbase + r;
                if (which == 0)      qb[(size_t)row * DM + c] = (bf16)v;
                else if (which == 1) kb[(size_t)row * DM + c] = (bf16)v;
                else {
                    const int n = row >> 11, s = row & (SQ - 1);
                    const int h = c >> 6, hd = c & 63;
                    vtb[((size_t)(((n << 3) | h) << 6 | hd) << 11) | s] = (bf16)v;
                }
            }
        }
    }
}

// ---------------------------------------------------------------------------
// Flash attention, R7: q=64 per wave. Block: one (n,h,kvhalf), 256 q-rows
// (4 waves x 64 q), 16 kv-tiles of 64. Grid 512 = 2 blocks/CU.
// S^T = K·Q^T: lane holds q=l15, kv=quad*4+r == K=16 PV A-layout (reg-P).
// Each Vt b64 read feeds 4 PV MFMAs; kf/staging amortized over 64 q.
// Writes UNNORMALIZED O (bf16) + lsum (fp32) partials; combine divides.
// ---------------------------------------------------------------------------
__global__ __launch_bounds__(256, 2) void attn_kernel(
    const bf16* __restrict__ qb, const bf16* __restrict__ kb,
    const bf16* __restrict__ vtb,
    bf16* __restrict__ opart0, bf16* __restrict__ opart1,
    float* __restrict__ lpart)
{
    __shared__ alignas(16) bf16 Kt[2][64][72];
    __shared__ alignas(16) bf16 Vt[2 * 64 * 68];
    const int tid = threadIdx.x;
    const int w = tid >> 6, lane = tid & 63;
    const int l15 = lane & 15, quad = lane >> 4;
    const int id = blockIdx.x;          // id&7 fixed per (nh,kvhalf) -> XCD
    const int kvhalf = id & 1;
    const int nh = (id >> 1) & 31;
    const int qblk = id >> 6;           // [0,8)
    const int n = nh >> 3, h = nh & 7;
    const int q0 = qblk * 256 + w * 64;
    const int kvbase = kvhalf * (SQ / 2);
    const bf16* qbase = qb + (size_t)n * SQ * DM + h * HD;
    const bf16* kbase = kb + (size_t)n * SQ * DM + h * HD;
    const bf16* vbase = vtb + (size_t)nh * HD * SQ;

    // Q fragments (B-operand of S^T: n=q=l15, k=d=quad*8+j), 4 mi tiles
    bf16x8 qf[4][2];
    #pragma unroll
    for (int mi = 0; mi < 4; mi++)
        #pragma unroll
        for (int hh = 0; hh < 2; hh++)
            qf[mi][hh] = *(const bf16x8*)(qbase + (size_t)(q0 + mi*16 + l15) * DM + hh*32 + quad*8);

    f32x4 o[4][4] = {};
    float lsum[4] = {0.f, 0.f, 0.f, 0.f};

    // staging: thread covers (srow, seg..seg+16) of the 64x64 tile
    const int srow = tid >> 2, seg = (tid & 3) * 16;
    const bf16* krow = kbase + (size_t)(kvbase + srow) * DM + seg;  // K rows = kv
    const bf16* vrow = vbase + (size_t)srow * SQ + kvbase + seg;    // V rows = hd

    auto storeV = [&](int buf, bf16x8 a, bf16x8 b) {
        bf16* d = &Vt[(buf * 64 + srow) * 68 + seg];
        bf16x4 p0, p1, p2, p3;
        #pragma unroll
        for (int i = 0; i < 4; i++) { p0[i]=a[i]; p1[i]=a[i+4]; p2[i]=b[i]; p3[i]=b[i+4]; }
        *(bf16x4*)(d)      = p0;
        *(bf16x4*)(d + 4)  = p1;
        *(bf16x4*)(d + 8)  = p2;
        *(bf16x4*)(d + 12) = p3;
    };

    { // prologue: stage tile 0 of this half
        bf16x8 k0 = *(const bf16x8*)(krow);
        bf16x8 k1 = *(const bf16x8*)(krow + 8);
        bf16x8 v0 = *(const bf16x8*)(vrow);
        bf16x8 v1 = *(const bf16x8*)(vrow + 8);
        *(bf16x8*)&Kt[0][srow][seg]     = k0;
        *(bf16x8*)&Kt[0][srow][seg + 8] = k1;
        storeV(0, v0, v1);
    }

    const int NT = SQ / 128;   // 16 tiles per half
    for (int jt = 0; jt < NT; jt++) {
        const int buf = jt & 1;
        __syncthreads();   // buf writes visible; prev iter's reads complete
        const bool pre = (jt + 1 < NT);
        bf16x8 k0, k1, v0, v1;
        if (pre) {         // next tile's global loads issued early
            const bf16* kp = krow + (size_t)(jt + 1) * 64 * DM;
            const bf16* vp = vrow + (jt + 1) * 64;
            k0 = *(const bf16x8*)(kp);
            k1 = *(const bf16x8*)(kp + 8);
            v0 = *(const bf16x8*)(vp);
            v1 = *(const bf16x8*)(vp + 8);
        }

        #pragma unroll
        for (int s4 = 0; s4 < 4; s4++) {
            // K A-frag (m=kv), Q B-frag -> S^T[kv][q]
            bf16x8 kf0 = *(const bf16x8*)&Kt[buf][s4*16 + l15][quad*8];
            bf16x8 kf1 = *(const bf16x8*)&Kt[buf][s4*16 + l15][32 + quad*8];
            bf16x4 pf[4];
            #pragma unroll
            for (int mi = 0; mi < 4; mi++) {
                f32x4 sacc = {};
                sacc = MFMA16(kf0, qf[mi][0], sacc);
                sacc = MFMA16(kf1, qf[mi][1], sacc);
                float p0 = fast_exp2(sacc[0]);
                float p1 = fast_exp2(sacc[1]);
                float p2 = fast_exp2(sacc[2]);
                float p3 = fast_exp2(sacc[3]);
                lsum[mi] += (p0 + p1) + (p2 + p3);
                bf16x4 pk;
                pk[0] = (bf16)p0; pk[1] = (bf16)p1;
                pk[2] = (bf16)p2; pk[3] = (bf16)p3;
                pf[mi] = pk;       // == K=16 A-frag: q=l15, kv=quad*4+j
            }
            // O[q][hd] += P V  (K=16 per s4 chunk); vf reused by 4 mi tiles
            #pragma unroll
            for (int d4 = 0; d4 < 4; d4++) {
                bf16x4 vf = *(const bf16x4*)&Vt[(buf*64 + d4*16 + l15) * 68 + s4*16 + quad*4];
                #pragma unroll
                for (int mi = 0; mi < 4; mi++)
                    o[mi][d4] = mfma_k16(pf[mi], vf, o[mi][d4]);
            }
        }

        if (pre) {
            *(bf16x8*)&Kt[buf^1][srow][seg]     = k0;
            *(bf16x8*)&Kt[buf^1][srow][seg + 8] = k1;
            storeV(buf^1, v0, v1);
        }
    }

    // lsum lives at q=l15 per quad; reduce across quads, write fp32 partials
    #pragma unroll
    for (int mi = 0; mi < 4; mi++) {
        lsum[mi] += __shfl_xor(lsum[mi], 16, 64);
        lsum[mi] += __shfl_xor(lsum[mi], 32, 64);
    }
    if (lane < 16) {
        const int qg = (nh << 11) + q0 + lane;   // nh*2048 + q
        #pragma unroll
        for (int mi = 0; mi < 4; mi++)
            lpart[(kvhalf << 16) + qg + mi * 16] = lsum[mi];
    }

    // write unnormalized O partial (bf16)
    bf16* op = kvhalf ? opart1 : opart0;
    #pragma unroll
    for (int mi = 0; mi < 4; mi++) {
        #pragma unroll
        for (int d4 = 0; d4 < 4; d4++) {
            const int col = h * HD + d4 * 16 + l15;
            #pragma unroll
            for (int r = 0; r < 4; r++) {
                const int row = n * SQ + q0 + mi*16 + quad*4 + r;
                op[(size_t)row * DM + col] = (bf16)o[mi][d4][r];
            }
        }
    }
}

// combine: yb = (O0 + O1) / (l0 + l1).  yb may alias o0 (same-thread RMW).
__global__ __launch_bounds__(256) void attn_combine_kernel(
    const bf16* o0, const bf16* o1, const float* __restrict__ lpart,
    bf16* yb)
{
    const int w = threadIdx.x >> 6, lane = threadIdx.x & 63;
    const size_t row = (size_t)blockIdx.x * 4 + w;
    const int q = (int)(row & (SQ - 1));
    const int nh = (int)(row >> 11) * 8 + (lane >> 3);
    const float rl = 1.f / (lpart[(nh << 11) + q] + lpart[(1 << 16) + (nh << 11) + q]);
    const size_t base = row * DM + lane * 8;
    bf16x8 a = *(const bf16x8*)(o0 + base);
    bf16x8 b = *(const bf16x8*)(o1 + base);
    bf16x8 y;
    #pragma unroll
    for (int i = 0; i < 8; i++)
        y[i] = (bf16)(((float)a[i] + (float)b[i]) * rl);
    *(bf16x8*)(yb + base) = y;
}

// ---------------------------------------------------------------------------
// Residual + LayerNorm: out = LN(res + add) * g + beta. One wave per row.
// ---------------------------------------------------------------------------
__global__ __launch_bounds__(256) void ln_kernel(
    const float* __restrict__ res, const float* __restrict__ add,
    const float* __restrict__ g, const float* __restrict__ beta,
    float* __restrict__ outf, bf16* __restrict__ outb)
{
    const int w = threadIdx.x >> 6, lane = threadIdx.x & 63;
    const size_t row = (size_t)blockIdx.x * 4 + w;
    const float4* rp = (const float4*)(res + row * DM);
    const float4* ap = (const float4*)(add + row * DM);
    float4 v[2];
    float s = 0.f, s2 = 0.f;
    #pragma unroll
    for (int i = 0; i < 2; i++) {
        const int idx = i * 64 + lane;
        float4 a = rp[idx], c = ap[idx];
        float x0 = a.x + c.x, x1 = a.y + c.y, x2 = a.z + c.z, x3 = a.w + c.w;
        v[i] = make_float4(x0, x1, x2, x3);
        s  += x0 + x1 + x2 + x3;
        s2 += x0*x0 + x1*x1 + x2*x2 + x3*x3;
    }
    for (int m = 1; m < 64; m <<= 1) {
        s  += __shfl_xor(s,  m, 64);
        s2 += __shfl_xor(s2, m, 64);
    }
    const float mean = s * (1.f / DM);
    const float var  = s2 * (1.f / DM) - mean * mean;
    const float rstd = rsqrtf(var + 1e-5f);
    #pragma unroll
    for (int i = 0; i < 2; i++) {
        const int idx = i * 64 + lane;
        float4 gw = ((const float4*)g)[idx], bw = ((const float4*)beta)[idx];
        float o0 = (v[i].x - mean) * rstd * gw.x + bw.x;
        float o1 = (v[i].y - mean) * rstd * gw.y + bw.y;
        float o2 = (v[i].z - mean) * rstd * gw.z + bw.z;
        float o3 = (v[i].w - mean) * rstd * gw.w + bw.w;
        ((float4*)(outf + row * DM))[idx] = make_float4(o0, o1, o2, o3);
        union { bf16 h[4]; uint2 u; } pk;
        pk.h[0] = (bf16)o0; pk.h[1] = (bf16)o1; pk.h[2] = (bf16)o2; pk.h[3] = (bf16)o3;
        *(uint2*)(outb + row * DM + idx * 4) = pk.u;
    }
}

// ---------------------------------------------------------------------------
extern "C" void kernel_launch(void* const* d_in, const int* in_sizes, int n_in,
                              void* d_out, int out_size, void* d_ws, size_t ws_size,
                              hipStream_t stream)
{
    const float* features = (const float*)d_in[0];
    const float* Wq  = (const float*)d_in[1];
    const float* bq  = (const float*)d_in[2];
    const float* Wk  = (const float*)d_in[3];
    const float* bk  = (const float*)d_in[4];
    const float* Wv  = (const float*)d_in[5];
    const float* bv  = (const float*)d_in[6];
    const float* Wo  = (const float*)d_in[7];
    const float* bo  = (const float*)d_in[8];
    const float* W1  = (const float*)d_in[9];
    const float* b1  = (const float*)d_in[10];
    const float* W2  = (const float*)d_in[11];
    const float* b2  = (const float*)d_in[12];
    const float* ln1w = (const float*)d_in[13];
    const float* ln1b = (const float*)d_in[14];
    const float* ln2w = (const float*)d_in[15];
    const float* ln2b = (const float*)d_in[16];
    float* outp = (float*)d_out;

    char* p = (char*)d_ws;
    size_t off = 0;
    auto alloc = [&](size_t bytes) { void* r = p + off; off = (off + bytes + 255) & ~(size_t)255; return r; };
    const size_t tokD = (size_t)MTOK * DM;
    float* x     = (float*)alloc(tokD * 4);
    float* tmp   = (float*)alloc(tokD * 4);
    bf16* xb     = (bf16*)alloc(tokD * 2);
    bf16* qb     = (bf16*)alloc(tokD * 2);
    bf16* kb     = (bf16*)alloc(tokD * 2);
    bf16* vtb    = (bf16*)alloc(tokD * 2);
    bf16* yb     = (bf16*)alloc(tokD * 2);   // doubles as O partial 0
    bf16* opart1 = (bf16*)alloc(tokD * 2);
    float* lpart = (float*)alloc(2 * 65536 * 4);
    bf16* ffh    = (bf16*)alloc((size_t)MTOK * FFP * 2);
    bf16* wqkvt  = (bf16*)alloc((size_t)NL * 3 * DM * DM * 2);
    bf16* wot    = (bf16*)alloc((size_t)NL * DM * DM * 2);
    bf16* w1t    = (bf16*)alloc((size_t)NL * FFP * DM * 2);
    bf16* w2t    = (bf16*)alloc((size_t)NL * DM * FFP * 2);
    (void)ws_size; (void)in_sizes; (void)n_in; (void)out_size;

    convw_kernel<<<dim3(16, 16, NL * 6), 256, 0, stream>>>(
        Wq, Wk, Wv, Wo, W1, W2, wqkvt, wot, w1t, w2t);

    posenc_kernel<<<MTOK, 256, 0, stream>>>(features, x, xb);

    for (int l = 0; l < NL; l++) {
        const bf16* wqkvt_l = wqkvt + (size_t)l * 3 * DM * DM;
        gemm128_qkv_kernel<<<dim3(MTOK / 128, 1536 / 128), 256, 0, stream>>>(
            xb, wqkvt_l, bq + l*DM, bk + l*DM, bv + l*DM, qb, kb, vtb);
        attn_kernel<<<512, 256, 0, stream>>>(qb, kb, vtb, yb, opart1, lpart);
        attn_combine_kernel<<<MTOK / 4, 256, 0, stream>>>(yb, opart1, lpart, yb);
        gemm64_kernel<<<dim3(MTOK / 128, DM / 64), 256, 0, stream>>>(
            yb, wot + (size_t)l*DM*DM, bo + l*DM, DM, tmp, nullptr, DM, DM, 0);
        ln_kernel<<<MTOK / 4, 256, 0, stream>>>(x, tmp, ln1w + l*DM, ln1b + l*DM, x, xb);
        gemm64_kernel<<<dim3(MTOK / 128, FFP / 64), 256, 0, stream>>>(
            xb, w1t + (size_t)l*FFP*DM, b1 + l*FF, FF, nullptr, ffh, DM, FFP, 2);
        gemm64_kernel<<<dim3(MTOK / 128, DM / 64), 256, 0, stream>>>(
            ffh, w2t + (size_t)l*DM*FFP, b2 + l*DM, DM, tmp, nullptr, FFP, DM, 0);
        float* outdst = (l == NL - 1) ? outp : x;
        ln_kernel<<<MTOK / 4, 256, 0, stream>>>(x, tmp, ln2w + l*DM, ln2b + l*DM, outdst, xb);
    }
}

// Round 8
// 627.879 us; speedup vs baseline: 1.1955x; 1.0231x over previous
//
#include <hip/hip_runtime.h>
#include <hip/hip_bf16.h>
#include <cstdint>

// ---------------------------------------------------------------------------
// ImageEncoder: 4-layer transformer encoder, N=4 S=2048 D=512 H=8 HD=64 F=200.
// fp32 residual stream + bf16 MFMA.
// R8: attn is latency/issue-bound within waves (R6: +occupancy = +1%;
// R7: +ILP = +9%). (a) PV via K=32 MFMA using the kv-permutation trick
// (S^T chunk pair == permuted K=32 A-frag; V read as two b64) -> 64->32 PV
// MFMAs/iter. (b) lsum via P*ones MFMA (8/iter) replaces 48 VALU adds +
// epilogue shuffles. (c) combine fused into Wo GEMM A-staging (VGPR path,
// per-head rl), removing 4 dispatches + 24MB traffic.
// ---------------------------------------------------------------------------

typedef __bf16 bf16;
typedef __bf16 bf16x8 __attribute__((ext_vector_type(8)));
typedef __bf16 bf16x4 __attribute__((ext_vector_type(4)));
typedef float f32x4 __attribute__((ext_vector_type(4)));

#define MFMA16(a, b, c) __builtin_amdgcn_mfma_f32_16x16x32_bf16((a), (b), (c), 0, 0, 0)

static constexpr int NB   = 4;
static constexpr int SQ   = 2048;
static constexpr int DM   = 512;
static constexpr int NH   = 8;
static constexpr int HD   = 64;
static constexpr int NL   = 4;
static constexpr int FF   = 200;
static constexpr int FFP  = 256;
static constexpr int MTOK = NB * SQ; // 8192

__device__ __forceinline__ float fast_exp2(float x) {
#if __has_builtin(__builtin_amdgcn_exp2f)
    return __builtin_amdgcn_exp2f(x);
#else
    return exp2f(x);
#endif
}

// async global->LDS, 16 bytes per lane
__device__ __forceinline__ void gld16(bf16* l, const bf16* g) {
    __builtin_amdgcn_global_load_lds(
        (const __attribute__((address_space(1))) void*)g,
        (__attribute__((address_space(3))) void*)l, 16, 0, 0);
}

// ---------------------------------------------------------------------------
// Weight convert + transpose:  src fp32 [K, Nsrc]  ->  dst bf16 [Npad, Kpad]
// ---------------------------------------------------------------------------
__global__ __launch_bounds__(256) void convw_kernel(
    const float* __restrict__ Wq, const float* __restrict__ Wk,
    const float* __restrict__ Wv, const float* __restrict__ Wo,
    const float* __restrict__ W1, const float* __restrict__ W2,
    bf16* __restrict__ wqkvt, bf16* __restrict__ wot,
    bf16* __restrict__ w1t, bf16* __restrict__ w2t)
{
    __shared__ float tile[32][33];
    const int z = blockIdx.z, l = z / 6, which = z % 6;
    const float* src; bf16* dst; int K, Nsrc, Npad, Kpad;
    switch (which) {
        case 0: src = Wq + (size_t)l*DM*DM; dst = wqkvt + (size_t)(l*3+0)*DM*DM; K=DM; Nsrc=DM; Npad=DM; Kpad=DM; break;
        case 1: src = Wk + (size_t)l*DM*DM; dst = wqkvt + (size_t)(l*3+1)*DM*DM; K=DM; Nsrc=DM; Npad=DM; Kpad=DM; break;
        case 2: src = Wv + (size_t)l*DM*DM; dst = wqkvt + (size_t)(l*3+2)*DM*DM; K=DM; Nsrc=DM; Npad=DM; Kpad=DM; break;
        case 3: src = Wo + (size_t)l*DM*DM; dst = wot   + (size_t)l*DM*DM;       K=DM; Nsrc=DM; Npad=DM; Kpad=DM; break;
        case 4: src = W1 + (size_t)l*DM*FF; dst = w1t   + (size_t)l*FFP*DM;      K=DM; Nsrc=FF; Npad=FFP; Kpad=DM; break;
        default:src = W2 + (size_t)l*FF*DM; dst = w2t   + (size_t)l*DM*FFP;      K=FF; Nsrc=DM; Npad=DM; Kpad=FFP; break;
    }
    const int k0 = blockIdx.x * 32, n0 = blockIdx.y * 32;
    if (k0 >= Kpad || n0 >= Npad) return;
    const int tr = threadIdx.x >> 3, tc = (threadIdx.x & 7) * 4;
    for (int c = 0; c < 4; c++) {
        int sr = k0 + tr, sc = n0 + tc + c;
        tile[tr][tc + c] = (sr < K && sc < Nsrc) ? src[(size_t)sr * Nsrc + sc] : 0.f;
    }
    __syncthreads();
    const int dr = n0 + tr;
    if (dr < Npad) {
        for (int c = 0; c < 4; c++) {
            int dc = k0 + tc + c;
            if (dc < Kpad) dst[(size_t)dr * Kpad + dc] = (bf16)tile[tc + c][tr];
        }
    }
}

// ---------------------------------------------------------------------------
// Positional encoding add + cast
// ---------------------------------------------------------------------------
__global__ __launch_bounds__(256) void posenc_kernel(
    const float* __restrict__ f, float* __restrict__ x, bf16* __restrict__ xb)
{
    const int t = blockIdx.x * 256 + threadIdx.x;
    const int d2 = t & 255, row = t >> 8, s = row & (SQ - 1);
    const float kfac = -0.03597789207803197f;           // -2*ln(10000)/512
    float dv = __expf((float)d2 * kfac);
    float ang = (float)s * dv;
    float pe0 = sinf(ang), pe1 = cosf(ang);
    const size_t base = (size_t)row * DM + d2 * 2;
    float2 fv = *(const float2*)(f + base);
    float o0 = fv.x + pe0, o1 = fv.y + pe1;
    *(float2*)(x + base) = make_float2(o0, o1);
    union { bf16 h[2]; unsigned int u; } pk;
    pk.h[0] = (bf16)o0; pk.h[1] = (bf16)o1;
    *(unsigned int*)(xb + base) = pk.u;
}

// ---------------------------------------------------------------------------
// m97-style GEMM core: block tile 128x128, BK=32, 4 waves (2x2 of 64x64).
// ---------------------------------------------------------------------------
__device__ __forceinline__ void gemm128_core(
    const bf16* __restrict__ A, const bf16* __restrict__ Wt, int K,
    int m0, int n0, bf16* As, bf16* Bs, f32x4 (&acc)[4][4])
{
    const int tid = threadIdx.x;
    const int w = tid >> 6, lane = tid & 63;
    const int l15 = lane & 15, quad = lane >> 4;
    const int srow = w * 16 + (lane >> 2);
    const int scol = (lane & 3) * 8;
    const bf16* Ag = A  + (size_t)(m0 + srow) * K + scol;
    const bf16* Bg = Wt + (size_t)(n0 + srow) * K + scol;
    bf16* AsW = As + w * 512;
    bf16* BsW = Bs + w * 512;
    const int wm = (w >> 1) * 64, wn = (w & 1) * 64;

    for (int k0 = 0; k0 < K; k0 += 32) {
        __syncthreads();
        gld16(AsW,        Ag + k0);
        gld16(AsW + 2048, Ag + (size_t)64 * K + k0);
        gld16(BsW,        Bg + k0);
        gld16(BsW + 2048, Bg + (size_t)64 * K + k0);
        asm volatile("s_waitcnt vmcnt(0)" ::: "memory");
        __syncthreads();

        bf16x8 af[4], bfr[4];
        #pragma unroll
        for (int i = 0; i < 4; i++)
            af[i] = *(const bf16x8*)&As[(wm + i * 16 + l15) * 32 + quad * 8];
        #pragma unroll
        for (int j = 0; j < 4; j++)
            bfr[j] = *(const bf16x8*)&Bs[(wn + j * 16 + l15) * 32 + quad * 8];
        #pragma unroll
        for (int i = 0; i < 4; i++)
            #pragma unroll
            for (int j = 0; j < 4; j++)
                acc[i][j] = MFMA16(af[i], bfr[j], acc[i][j]);
    }
}

// 128x64-tile GEMM (wave-tile 64x32). modes: 0 fp32, 1 bf16, 2 bf16 relu
__global__ __launch_bounds__(256, 3) void gemm64_kernel(
    const bf16* __restrict__ A, const bf16* __restrict__ Wt,
    const float* __restrict__ bias, int nbias,
    float* __restrict__ outf, bf16* __restrict__ outb,
    int K, int Nc, int mode)
{
    __shared__ alignas(16) bf16 As[128 * 32];
    __shared__ alignas(16) bf16 Bs[64 * 32];
    const int m0 = blockIdx.x * 128, n0 = blockIdx.y * 64;
    const int tid = threadIdx.x;
    const int w = tid >> 6, lane = tid & 63;
    const int l15 = lane & 15, quad = lane >> 4;
    const int srow = w * 16 + (lane >> 2);
    const int scol = (lane & 3) * 8;
    const bf16* Ag = A  + (size_t)(m0 + srow) * K + scol;
    const bf16* Bg = Wt + (size_t)(n0 + srow) * K + scol;
    bf16* AsW = As + w * 512;
    bf16* BsW = Bs + w * 512;
    const int wm = (w >> 1) * 64, wn = (w & 1) * 32;
    f32x4 acc[4][2] = {};

    for (int k0 = 0; k0 < K; k0 += 32) {
        __syncthreads();
        gld16(AsW,        Ag + k0);
        gld16(AsW + 2048, Ag + (size_t)64 * K + k0);
        gld16(BsW,        Bg + k0);
        asm volatile("s_waitcnt vmcnt(0)" ::: "memory");
        __syncthreads();

        bf16x8 af[4], bfr[2];
        #pragma unroll
        for (int i = 0; i < 4; i++)
            af[i] = *(const bf16x8*)&As[(wm + i * 16 + l15) * 32 + quad * 8];
        #pragma unroll
        for (int j = 0; j < 2; j++)
            bfr[j] = *(const bf16x8*)&Bs[(wn + j * 16 + l15) * 32 + quad * 8];
        #pragma unroll
        for (int i = 0; i < 4; i++)
            #pragma unroll
            for (int j = 0; j < 2; j++)
                acc[i][j] = MFMA16(af[i], bfr[j], acc[i][j]);
    }

    #pragma unroll
    for (int j = 0; j < 2; j++) {
        const int col = n0 + wn + j * 16 + l15;
        const float bv = (col < nbias) ? bias[col] : 0.f;
        #pragma unroll
        for (int i = 0; i < 4; i++) {
            const int rbase = m0 + wm + i * 16 + quad * 4;
            #pragma unroll
            for (int r = 0; r < 4; r++) {
                float v = acc[i][j][r] + bv;
                const int row = rbase + r;
                const size_t idx = (size_t)row * Nc + col;
                if (mode == 0)      outf[idx] = v;
                else if (mode == 1) outb[idx] = (bf16)v;
                else                outb[idx] = (bf16)fmaxf(v, 0.f);
            }
        }
    }
}

// Wo GEMM with fused attn-combine: A = bf16((o0+o1)*rl[head]) staged through
// VGPRs (coalesced b128 loads, per-head rl in regs). 128x64 tile, grid (64,8).
__global__ __launch_bounds__(256, 3) void gemm_wo_kernel(
    const bf16* __restrict__ o0, const bf16* __restrict__ o1,
    const float* __restrict__ lpart,
    const bf16* __restrict__ Wt, const float* __restrict__ bias,
    float* __restrict__ outf)
{
    __shared__ alignas(16) bf16 As[128 * 32];
    __shared__ alignas(16) bf16 Bs[64 * 32];
    const int m0 = blockIdx.x * 128, n0 = blockIdx.y * 64;
    const int tid = threadIdx.x;
    const int w = tid >> 6, lane = tid & 63;
    const int l15 = lane & 15, quad = lane >> 4;
    const int srow = w * 16 + (lane >> 2);
    const int scol = (lane & 3) * 8;
    const int row0 = m0 + srow, row1 = row0 + 64;
    const bf16* Bg = Wt + (size_t)(n0 + srow) * DM + scol;
    bf16* BsW = Bs + w * 512;
    bf16* AsD0 = As + w * 512 + lane * 8;   // 16B/lane, contiguous in lane order
    bf16* AsD1 = AsD0 + 2048;
    const int wm = (w >> 1) * 64, wn = (w & 1) * 32;

    // per-head reciprocal softmax denominators for this thread's two A rows
    const int b0 = (((row0 >> 11) * 8) << 11) | (row0 & (SQ - 1));
    const int b1 = (((row1 >> 11) * 8) << 11) | (row1 & (SQ - 1));
    float rl0[8], rl1[8];
    #pragma unroll
    for (int h = 0; h < 8; h++) {
        rl0[h] = 1.f / (lpart[b0 + (h << 11)] + lpart[65536 + b0 + (h << 11)]);
        rl1[h] = 1.f / (lpart[b1 + (h << 11)] + lpart[65536 + b1 + (h << 11)]);
    }

    const bf16* A0g  = o0 + (size_t)row0 * DM + scol;
    const bf16* A0g2 = o0 + (size_t)row1 * DM + scol;
    const bf16* A1g  = o1 + (size_t)row0 * DM + scol;
    const bf16* A1g2 = o1 + (size_t)row1 * DM + scol;
    f32x4 acc[4][2] = {};

    #pragma unroll
    for (int h = 0; h < 8; h++) {
        #pragma unroll
        for (int kk = 0; kk < 2; kk++) {
            const int k0 = h * 64 + kk * 32;
            __syncthreads();
            bf16x8 a0 = *(const bf16x8*)(A0g  + k0);
            bf16x8 c0 = *(const bf16x8*)(A1g  + k0);
            bf16x8 a1 = *(const bf16x8*)(A0g2 + k0);
            bf16x8 c1 = *(const bf16x8*)(A1g2 + k0);
            gld16(BsW, Bg + k0);
            bf16x8 s0, s1;
            #pragma unroll
            for (int i = 0; i < 8; i++) {
                s0[i] = (bf16)(((float)a0[i] + (float)c0[i]) * rl0[h]);
                s1[i] = (bf16)(((float)a1[i] + (float)c1[i]) * rl1[h]);
            }
            *(bf16x8*)AsD0 = s0;
            *(bf16x8*)AsD1 = s1;
            asm volatile("s_waitcnt vmcnt(0)" ::: "memory");
            __syncthreads();

            bf16x8 af[4], bfr[2];
            #pragma unroll
            for (int i = 0; i < 4; i++)
                af[i] = *(const bf16x8*)&As[(wm + i * 16 + l15) * 32 + quad * 8];
            #pragma unroll
            for (int j = 0; j < 2; j++)
                bfr[j] = *(const bf16x8*)&Bs[(wn + j * 16 + l15) * 32 + quad * 8];
            #pragma unroll
            for (int i = 0; i < 4; i++)
                #pragma unroll
                for (int j = 0; j < 2; j++)
                    acc[i][j] = MFMA16(af[i], bfr[j], acc[i][j]);
        }
    }

    #pragma unroll
    for (int j = 0; j < 2; j++) {
        const int col = n0 + wn + j * 16 + l15;
        const float bv = bias[col];
        #pragma unroll
        for (int i = 0; i < 4; i++) {
            const int rbase = m0 + wm + i * 16 + quad * 4;
            #pragma unroll
            for (int r = 0; r < 4; r++)
                outf[(size_t)(rbase + r) * DM + col] = acc[i][j][r] + bv;
        }
    }
}

// fused QKV (128x128 core). Q gets (1/sqrt(HD))*log2(e) folded in;
// V written transposed to [n,h,hd,s].
__global__ __launch_bounds__(256, 3) void gemm128_qkv_kernel(
    const bf16* __restrict__ xb, const bf16* __restrict__ Wt,
    const float* __restrict__ bq, const float* __restrict__ bk,
    const float* __restrict__ bv,
    bf16* __restrict__ qb, bf16* __restrict__ kb, bf16* __restrict__ vtb)
{
    __shared__ alignas(16) bf16 As[128 * 32];
    __shared__ alignas(16) bf16 Bs[128 * 32];
    const int m0 = blockIdx.x * 128, n0 = blockIdx.y * 128;
    f32x4 acc[4][4] = {};
    gemm128_core(xb, Wt, DM, m0, n0, As, Bs, acc);

    const int lane = threadIdx.x & 63;
    const int l15 = lane & 15, quad = lane >> 4;
    const int w = threadIdx.x >> 6;
    const int wm = (w >> 1) * 64, wn = (w & 1) * 64;
    const int which = n0 >> 9;
    const float* bias = (which == 0) ? bq : (which == 1) ? bk : bv;
    // 0.125 = 1/sqrt(64); *1.44269504 so attn can use exp2 directly
    const float scale = (which == 0) ? 0.18033688f : 1.f;
    #pragma unroll
    for (int j = 0; j < 4; j++) {
        const int c = (n0 & 511) + wn + j * 16 + l15;
        const float bvv = bias[c];
        #pragma unroll
        for (int i = 0; i < 4; i++) {
            const int rbase = m0 + wm + i * 16 + quad * 4;
            #pragma unroll
            for (int r = 0; r < 4; r++) {
                float v = (acc[i][j][r] + bvv) * scale;
                const int row = rbase + r;
                if (which == 0)      qb[(size_t)row * DM + c] = (bf16)v;
                else if (which == 1) kb[(size_t)row * DM + c] = (bf16)v;
                else {
                    const int n = row >> 11, s = row & (SQ - 1);
                    const int h = c >> 6, hd = c & 63;
                    vtb[((size_t)(((n << 3) | h) << 6 | hd) << 11) | s] = (bf16)v;
                }
            }
        }
    }
}

// ---------------------------------------------------------------------------
// Flash attention, R8. Block: one (n,h,kvhalf), 256 q (4 waves x 64 q),
// 16 kv-tiles of 64. Grid 512.
// S^T = K·Q^T (16x16x32): lane holds q=l15, kv=quad*4+r. The two 16-chunks
// of a 32-kv span concat to a PERMUTED K=32 A-frag (kv = {4q..4q+3} ∪
// {16+4q..16+4q+3} = pi(quad*8+j)); V read with the same permutation (two
// b64 at +0/+16) -> PV uses K=32 MFMA (32 instrs, was 64).
// lsum = P*ones via MFMA (8/iter): D[q][*] rows align with o's rows ->
// no VALU adds, no shuffles. Unnormalized O + lsum partials out.
// ---------------------------------------------------------------------------
__global__ __launch_bounds__(256, 2) void attn_kernel(
    const bf16* __restrict__ qb, const bf16* __restrict__ kb,
    const bf16* __restrict__ vtb,
    bf16* __restrict__ opart0, bf16* __restrict__ opart1,
    float* __restrict__ lpart)
{
    __shared__ alignas(16) bf16 Kt[2][64][72];
    __shared__ alignas(16) bf16 Vt[2 * 64 * 68];
    const int tid = threadIdx.x;
    const int w = tid >> 6, lane = tid & 63;
    const int l15 = lane & 15, quad = lane >> 4;
    const int id = blockIdx.x;          // id&7 fixed per (nh,kvhalf) -> XCD
    const int kvhalf = id & 1;
    const int nh = (id >> 1) & 31;
    const int qblk = id >> 6;           // [0,8)
    const int n = nh >> 3, h = nh & 7;
    const int q0 = qblk * 256 + w * 64;
    const int kvbase = kvhalf * (SQ / 2);
    const bf16* qbase = qb + (size_t)n * SQ * DM + h * HD;
    const bf16* kbase = kb + (size_t)n * SQ * DM + h * HD;
    const bf16* vbase = vtb + (size_t)nh * HD * SQ;

    // Q fragments (B-operand of S^T: n=q=l15, k=d=quad*8+j), 4 mi tiles
    bf16x8 qf[4][2];
    #pragma unroll
    for (int mi = 0; mi < 4; mi++)
        #pragma unroll
        for (int hh = 0; hh < 2; hh++)
            qf[mi][hh] = *(const bf16x8*)(qbase + (size_t)(q0 + mi*16 + l15) * DM + hh*32 + quad*8);

    bf16x8 ones8;
    #pragma unroll
    for (int i = 0; i < 8; i++) ones8[i] = (bf16)1.0f;

    f32x4 o[4][4] = {};
    f32x4 lacc[4] = {};

    // staging: thread covers (srow, seg..seg+16) of the 64x64 tile
    const int srow = tid >> 2, seg = (tid & 3) * 16;
    const bf16* krow = kbase + (size_t)(kvbase + srow) * DM + seg;  // K rows = kv
    const bf16* vrow = vbase + (size_t)srow * SQ + kvbase + seg;    // V rows = hd

    auto storeV = [&](int buf, bf16x8 a, bf16x8 b) {
        bf16* d = &Vt[(buf * 64 + srow) * 68 + seg];
        bf16x4 p0, p1, p2, p3;
        #pragma unroll
        for (int i = 0; i < 4; i++) { p0[i]=a[i]; p1[i]=a[i+4]; p2[i]=b[i]; p3[i]=b[i+4]; }
        *(bf16x4*)(d)      = p0;
        *(bf16x4*)(d + 4)  = p1;
        *(bf16x4*)(d + 8)  = p2;
        *(bf16x4*)(d + 12) = p3;
    };

    { // prologue: stage tile 0 of this half
        bf16x8 k0 = *(const bf16x8*)(krow);
        bf16x8 k1 = *(const bf16x8*)(krow + 8);
        bf16x8 v0 = *(const bf16x8*)(vrow);
        bf16x8 v1 = *(const bf16x8*)(vrow + 8);
        *(bf16x8*)&Kt[0][srow][seg]     = k0;
        *(bf16x8*)&Kt[0][srow][seg + 8] = k1;
        storeV(0, v0, v1);
    }

    const int NT = SQ / 128;   // 16 tiles per half
    for (int jt = 0; jt < NT; jt++) {
        const int buf = jt & 1;
        __syncthreads();   // buf writes visible; prev iter's reads complete
        const bool pre = (jt + 1 < NT);
        bf16x8 k0, k1, v0, v1;
        if (pre) {         // next tile's global loads issued early
            const bf16* kp = krow + (size_t)(jt + 1) * 64 * DM;
            const bf16* vp = vrow + (jt + 1) * 64;
            k0 = *(const bf16x8*)(kp);
            k1 = *(const bf16x8*)(kp + 8);
            v0 = *(const bf16x8*)(vp);
            v1 = *(const bf16x8*)(vp + 8);
        }

        #pragma unroll
        for (int sp = 0; sp < 2; sp++) {
            // two 16-row kv chunks of this 32-span
            bf16x8 kfA0 = *(const bf16x8*)&Kt[buf][sp*32 + l15][quad*8];
            bf16x8 kfA1 = *(const bf16x8*)&Kt[buf][sp*32 + l15][32 + quad*8];
            bf16x8 kfB0 = *(const bf16x8*)&Kt[buf][sp*32 + 16 + l15][quad*8];
            bf16x8 kfB1 = *(const bf16x8*)&Kt[buf][sp*32 + 16 + l15][32 + quad*8];
            bf16x8 pf[4];
            #pragma unroll
            for (int mi = 0; mi < 4; mi++) {
                f32x4 sa = {}, sb = {};
                sa = MFMA16(kfA0, qf[mi][0], sa);
                sa = MFMA16(kfA1, qf[mi][1], sa);
                sb = MFMA16(kfB0, qf[mi][0], sb);
                sb = MFMA16(kfB1, qf[mi][1], sb);
                bf16x8 p;
                #pragma unroll
                for (int r = 0; r < 4; r++) {
                    p[r]     = (bf16)fast_exp2(sa[r]);
                    p[r + 4] = (bf16)fast_exp2(sb[r]);
                }
                pf[mi] = p;                      // permuted K=32 A-frag
                lacc[mi] = MFMA16(p, ones8, lacc[mi]);   // row sums
            }
            // O[q][hd] += P V  (K=32, kv-permuted; V rows follow pi)
            #pragma unroll
            for (int d4 = 0; d4 < 4; d4++) {
                const bf16* vp2 = &Vt[(buf*64 + d4*16 + l15) * 68 + sp*32 + quad*4];
                bf16x4 vlo = *(const bf16x4*)(vp2);
                bf16x4 vhi = *(const bf16x4*)(vp2 + 16);
                bf16x8 vf;
                #pragma unroll
                for (int i = 0; i < 4; i++) { vf[i] = vlo[i]; vf[i+4] = vhi[i]; }
                #pragma unroll
                for (int mi = 0; mi < 4; mi++)
                    o[mi][d4] = MFMA16(pf[mi], vf, o[mi][d4]);
            }
        }

        if (pre) {
            *(bf16x8*)&Kt[buf^1][srow][seg]     = k0;
            *(bf16x8*)&Kt[buf^1][srow][seg + 8] = k1;
            storeV(buf^1, v0, v1);
        }
    }

    // lacc[mi][r] = lsum for q = q0 + mi*16 + quad*4 + r (same in every l15
    // lane). One lane per quad writes 4 contiguous floats.
    if (l15 == 0) {
        const int base = (kvhalf << 16) + (nh << 11) + q0 + quad * 4;
        #pragma unroll
        for (int mi = 0; mi < 4; mi++) {
            float4 v4 = make_float4(lacc[mi][0], lacc[mi][1], lacc[mi][2], lacc[mi][3]);
            *(float4*)&lpart[base + mi * 16] = v4;
        }
    }

    // write unnormalized O partial (bf16)
    bf16* op = kvhalf ? opart1 : opart0;
    #pragma unroll
    for (int mi = 0; mi < 4; mi++) {
        #pragma unroll
        for (int d4 = 0; d4 < 4; d4++) {
            const int col = h * HD + d4 * 16 + l15;
            #pragma unroll
            for (int r = 0; r < 4; r++) {
                const int row = n * SQ + q0 + mi*16 + quad*4 + r;
                op[(size_t)row * DM + col] = (bf16)o[mi][d4][r];
            }
        }
    }
}

// ---------------------------------------------------------------------------
// Residual + LayerNorm: out = LN(res + add) * g + beta. One wave per row.
// ---------------------------------------------------------------------------
__global__ __launch_bounds__(256) void ln_kernel(
    const float* __restrict__ res, const float* __restrict__ add,
    const float* __restrict__ g, const float* __restrict__ beta,
    float* __restrict__ outf, bf16* __restrict__ outb)
{
    const int w = threadIdx.x >> 6, lane = threadIdx.x & 63;
    const size_t row = (size_t)blockIdx.x * 4 + w;
    const float4* rp = (const float4*)(res + row * DM);
    const float4* ap = (const float4*)(add + row * DM);
    float4 v[2];
    float s = 0.f, s2 = 0.f;
    #pragma unroll
    for (int i = 0; i < 2; i++) {
        const int idx = i * 64 + lane;
        float4 a = rp[idx], c = ap[idx];
        float x0 = a.x + c.x, x1 = a.y + c.y, x2 = a.z + c.z, x3 = a.w + c.w;
        v[i] = make_float4(x0, x1, x2, x3);
        s  += x0 + x1 + x2 + x3;
        s2 += x0*x0 + x1*x1 + x2*x2 + x3*x3;
    }
    for (int m = 1; m < 64; m <<= 1) {
        s  += __shfl_xor(s,  m, 64);
        s2 += __shfl_xor(s2, m, 64);
    }
    const float mean = s * (1.f / DM);
    const float var  = s2 * (1.f / DM) - mean * mean;
    const float rstd = rsqrtf(var + 1e-5f);
    #pragma unroll
    for (int i = 0; i < 2; i++) {
        const int idx = i * 64 + lane;
        float4 gw = ((const float4*)g)[idx], bw = ((const float4*)beta)[idx];
        float o0 = (v[i].x - mean) * rstd * gw.x + bw.x;
        float o1 = (v[i].y - mean) * rstd * gw.y + bw.y;
        float o2 = (v[i].z - mean) * rstd * gw.z + bw.z;
        float o3 = (v[i].w - mean) * rstd * gw.w + bw.w;
        ((float4*)(outf + row * DM))[idx] = make_float4(o0, o1, o2, o3);
        union { bf16 h[4]; uint2 u; } pk;
        pk.h[0] = (bf16)o0; pk.h[1] = (bf16)o1; pk.h[2] = (bf16)o2; pk.h[3] = (bf16)o3;
        *(uint2*)(outb + row * DM + idx * 4) = pk.u;
    }
}

// ---------------------------------------------------------------------------
extern "C" void kernel_launch(void* const* d_in, const int* in_sizes, int n_in,
                              void* d_out, int out_size, void* d_ws, size_t ws_size,
                              hipStream_t stream)
{
    const float* features = (const float*)d_in[0];
    const float* Wq  = (const float*)d_in[1];
    const float* bq  = (const float*)d_in[2];
    const float* Wk  = (const float*)d_in[3];
    const float* bk  = (const float*)d_in[4];
    const float* Wv  = (const float*)d_in[5];
    const float* bv  = (const float*)d_in[6];
    const float* Wo  = (const float*)d_in[7];
    const float* bo  = (const float*)d_in[8];
    const float* W1  = (const float*)d_in[9];
    const float* b1  = (const float*)d_in[10];
    const float* W2  = (const float*)d_in[11];
    const float* b2  = (const float*)d_in[12];
    const float* ln1w = (const float*)d_in[13];
    const float* ln1b = (const float*)d_in[14];
    const float* ln2w = (const float*)d_in[15];
    const float* ln2b = (const float*)d_in[16];
    float* outp = (float*)d_out;

    char* p = (char*)d_ws;
    size_t off = 0;
    auto alloc = [&](size_t bytes) { void* r = p + off; off = (off + bytes + 255) & ~(size_t)255; return r; };
    const size_t tokD = (size_t)MTOK * DM;
    float* x     = (float*)alloc(tokD * 4);
    float* tmp   = (float*)alloc(tokD * 4);
    bf16* xb     = (bf16*)alloc(tokD * 2);
    bf16* qb     = (bf16*)alloc(tokD * 2);
    bf16* kb     = (bf16*)alloc(tokD * 2);
    bf16* vtb    = (bf16*)alloc(tokD * 2);
    bf16* opart0 = (bf16*)alloc(tokD * 2);
    bf16* opart1 = (bf16*)alloc(tokD * 2);
    float* lpart = (float*)alloc(2 * 65536 * 4);
    bf16* ffh    = (bf16*)alloc((size_t)MTOK * FFP * 2);
    bf16* wqkvt  = (bf16*)alloc((size_t)NL * 3 * DM * DM * 2);
    bf16* wot    = (bf16*)alloc((size_t)NL * DM * DM * 2);
    bf16* w1t    = (bf16*)alloc((size_t)NL * FFP * DM * 2);
    bf16* w2t    = (bf16*)alloc((size_t)NL * DM * FFP * 2);
    (void)ws_size; (void)in_sizes; (void)n_in; (void)out_size;

    convw_kernel<<<dim3(16, 16, NL * 6), 256, 0, stream>>>(
        Wq, Wk, Wv, Wo, W1, W2, wqkvt, wot, w1t, w2t);

    posenc_kernel<<<MTOK, 256, 0, stream>>>(features, x, xb);

    for (int l = 0; l < NL; l++) {
        const bf16* wqkvt_l = wqkvt + (size_t)l * 3 * DM * DM;
        gemm128_qkv_kernel<<<dim3(MTOK / 128, 1536 / 128), 256, 0, stream>>>(
            xb, wqkvt_l, bq + l*DM, bk + l*DM, bv + l*DM, qb, kb, vtb);
        attn_kernel<<<512, 256, 0, stream>>>(qb, kb, vtb, opart0, opart1, lpart);
        // tmp = combine(o0,o1,lpart) @ Wo + bo   (combine fused into staging)
        gemm_wo_kernel<<<dim3(MTOK / 128, DM / 64), 256, 0, stream>>>(
            opart0, opart1, lpart, wot + (size_t)l*DM*DM, bo + l*DM, tmp);
        ln_kernel<<<MTOK / 4, 256, 0, stream>>>(x, tmp, ln1w + l*DM, ln1b + l*DM, x, xb);
        gemm64_kernel<<<dim3(MTOK / 128, FFP / 64), 256, 0, stream>>>(
            xb, w1t + (size_t)l*FFP*DM, b1 + l*FF, FF, nullptr, ffh, DM, FFP, 2);
        gemm64_kernel<<<dim3(MTOK / 128, DM / 64), 256, 0, stream>>>(
            ffh, w2t + (size_t)l*DM*FFP, b2 + l*DM, DM, tmp, nullptr, FFP, DM, 0);
        float* outdst = (l == NL - 1) ? outp : x;
        ln_kernel<<<MTOK / 4, 256, 0, stream>>>(x, tmp, ln2w + l*DM, ln2b + l*DM, outdst, xb);
    }
}